// Round 1
// baseline (4380.830 us; speedup 1.0000x reference)
//
#include <hip/hip_runtime.h>
#include <math.h>

#define CDIM 256
#define HWD 4096
#define NPIX 32768
#define IDIM 1024
#define KC 1024

// ---------- depthwise conv 7x7 + bias: NCHW plane -> NHWC rows ----------
__global__ __launch_bounds__(256) void k_conv(const float* __restrict__ in,
                                              const float* __restrict__ cw,
                                              const float* __restrict__ cb,
                                              float* __restrict__ rows) {
  const int bc = blockIdx.x;            // b*256 + c
  const int b = bc >> 8, c = bc & 255;
  __shared__ float tile[70 * 72];
  const float* plane = in + (size_t)bc * HWD;
  for (int i = threadIdx.x; i < 70 * 70; i += 256) {
    const int r = i / 70, col = i - r * 70;
    const int h = r - 3, w = col - 3;
    float v = 0.0f;
    if ((unsigned)h < 64u && (unsigned)w < 64u) v = plane[h * 64 + w];
    tile[r * 72 + col] = v;
  }
  const float* wp = cw + c * 49;
  float wt[49];
#pragma unroll
  for (int i = 0; i < 49; ++i) wt[i] = wp[i];
  const float bias = cb[c];
  __syncthreads();
  for (int p = threadIdx.x; p < HWD; p += 256) {
    const int h = p >> 6, w = p & 63;
    float acc = bias;
#pragma unroll
    for (int kh = 0; kh < 7; ++kh)
#pragma unroll
      for (int kw = 0; kw < 7; ++kw)
        acc = fmaf(tile[(h + kh) * 72 + (w + kw)], wt[kh * 7 + kw], acc);
    rows[(size_t)(b * HWD + p) * CDIM + c] = acc;
  }
}

// ---------- LayerNorm over channels, in-place on NHWC rows ----------
__global__ __launch_bounds__(256) void k_ln(float* __restrict__ rows,
                                            const float* __restrict__ g,
                                            const float* __restrict__ bt) {
  const int n = blockIdx.x;
  const int t = threadIdx.x;
  float v = rows[(size_t)n * CDIM + t];
  __shared__ float red[4];
  __shared__ float bcast;
  const int w = t >> 6, l = t & 63;
  float s = v;
#pragma unroll
  for (int o = 32; o > 0; o >>= 1) s += __shfl_down(s, o);
  if (l == 0) red[w] = s;
  __syncthreads();
  if (t == 0) bcast = (red[0] + red[1] + red[2] + red[3]) * (1.0f / 256.0f);
  __syncthreads();
  const float mu = bcast;
  const float d = v - mu;
  float s2 = d * d;
#pragma unroll
  for (int o = 32; o > 0; o >>= 1) s2 += __shfl_down(s2, o);
  __syncthreads();
  if (l == 0) red[w] = s2;
  __syncthreads();
  if (t == 0)
    bcast = 1.0f / sqrtf((red[0] + red[1] + red[2] + red[3]) * (1.0f / 256.0f) + 1e-5f);
  __syncthreads();
  rows[(size_t)n * CDIM + t] = d * bcast * g[t] + bt[t];
}

// ---------- fc1 (N x 256 @ 256 x 1024) + bias + exact GELU ----------
__global__ __launch_bounds__(256) void k_fc1(const float* __restrict__ A,
                                             const float* __restrict__ Wt,
                                             const float* __restrict__ bias,
                                             float* __restrict__ Mout,
                                             int row0) {
  const int bx = blockIdx.x;
  const int mt = bx & 15, nt = bx >> 4;
  const int n0g = row0 + nt * 64;
  const int n0l = nt * 64;
  const int m0 = mt * 64;
  __shared__ float As[32 * 68];
  __shared__ float Bs[32 * 68];
  const int t = threadIdx.x;
  const int tr = t & 15, tc = t >> 4;
  float acc[4][4] = {};
  for (int kc = 0; kc < CDIM; kc += 32) {
#pragma unroll
    for (int i = 0; i < 2; ++i) {
      const int f = t + i * 256;
      const int n = f >> 3, j = (f & 7) << 2;
      const float4 v = *(const float4*)(A + (size_t)(n0g + n) * CDIM + kc + j);
      As[(j + 0) * 68 + n] = v.x;
      As[(j + 1) * 68 + n] = v.y;
      As[(j + 2) * 68 + n] = v.z;
      As[(j + 3) * 68 + n] = v.w;
    }
#pragma unroll
    for (int i = 0; i < 2; ++i) {
      const int f = t + i * 256;
      const int k = f >> 4, m4 = (f & 15) << 2;
      *(float4*)(Bs + k * 68 + m4) = *(const float4*)(Wt + (size_t)(kc + k) * IDIM + m0 + m4);
    }
    __syncthreads();
#pragma unroll
    for (int k = 0; k < 32; ++k) {
      const float4 af = *(const float4*)(As + k * 68 + tr * 4);
      const float4 bf = *(const float4*)(Bs + k * 68 + tc * 4);
      const float av[4] = {af.x, af.y, af.z, af.w};
      const float bv[4] = {bf.x, bf.y, bf.z, bf.w};
#pragma unroll
      for (int i = 0; i < 4; ++i)
#pragma unroll
        for (int j = 0; j < 4; ++j) acc[i][j] = fmaf(av[i], bv[j], acc[i][j]);
    }
    __syncthreads();
  }
#pragma unroll
  for (int i = 0; i < 4; ++i) {
    const int nl = n0l + tr * 4 + i;
    float ov[4];
#pragma unroll
    for (int j = 0; j < 4; ++j) {
      const int m = m0 + tc * 4 + j;
      const float xx = acc[i][j] + bias[m];
      ov[j] = 0.5f * xx * (1.0f + erff(xx * 0.70710678118654752f));
    }
    float4 o;
    o.x = ov[0]; o.y = ov[1]; o.z = ov[2]; o.w = ov[3];
    *(float4*)(Mout + (size_t)nl * IDIM + m0 + tc * 4) = o;
  }
}

// ---------- GRN spatial sum-of-squares per (b, ch) ----------
__global__ __launch_bounds__(256) void k_grn_reduce(const float* __restrict__ M,
                                                    float* __restrict__ GX, int b0) {
  const int bx = blockIdx.x;
  const int lb = bx >> 4;
  const int b = b0 + lb;
  const int c0 = (bx & 15) << 6;
  const int t = threadIdx.x;
  const int ch = c0 + (t & 63);
  const int q = t >> 6;
  const float* base = M + (size_t)lb * HWD * IDIM + ch;
  float s = 0.0f;
  for (int p = q; p < HWD; p += 4) {
    const float v = base[(size_t)p * IDIM];
    s = fmaf(v, v, s);
  }
  __shared__ float red[256];
  red[t] = s;
  __syncthreads();
  if (q == 0) {
    const float tot = red[t] + red[t + 64] + red[t + 128] + red[t + 192];
    GX[(size_t)b * IDIM + ch] = sqrtf(tot);
  }
}

// ---------- GRN channel-mean + scale s = 1 + gg*nx ----------
__global__ __launch_bounds__(256) void k_grn_scale(const float* __restrict__ GX,
                                                   const float* __restrict__ gg,
                                                   float* __restrict__ S, int b0) {
  const int b = b0 + blockIdx.x;
  const int t = threadIdx.x;
  const float* gxb = GX + (size_t)b * IDIM;
  float s = gxb[t] + gxb[t + 256] + gxb[t + 512] + gxb[t + 768];
  const int w = t >> 6, l = t & 63;
#pragma unroll
  for (int o = 32; o > 0; o >>= 1) s += __shfl_down(s, o);
  __shared__ float red[4];
  __shared__ float bcast;
  if (l == 0) red[w] = s;
  __syncthreads();
  if (t == 0)
    bcast = 1.0f / ((red[0] + red[1] + red[2] + red[3]) * (1.0f / 1024.0f) + 1e-6f);
  __syncthreads();
  const float inv = bcast;
#pragma unroll
  for (int i = 0; i < 4; ++i) {
    const int c = t + i * 256;
    S[(size_t)b * IDIM + c] = fmaf(gg[c], gxb[c] * inv, 1.0f);
  }
}

// ---------- fc2 (N x 1024 @ 1024 x 256) with GRN scale on A, +bias +residual ----------
__global__ __launch_bounds__(256) void k_fc2(const float* __restrict__ M,
                                             const float* __restrict__ S,
                                             const float* __restrict__ GB,
                                             const float* __restrict__ Wt,
                                             const float* __restrict__ bias,
                                             const float* __restrict__ xin,
                                             float* __restrict__ xout,
                                             float* __restrict__ rowsOut,
                                             int row0) {
  const int bx = blockIdx.x;
  const int mt = bx & 3, nt = bx >> 2;
  const int n0g = row0 + nt * 64;
  const int n0l = nt * 64;
  const int m0 = mt * 64;
  const int bglob = n0g >> 12;
  __shared__ float As[32 * 68];
  __shared__ float Bs[32 * 68];
  const int t = threadIdx.x;
  const int tr = t & 15, tc = t >> 4;
  float acc[4][4] = {};
  for (int kc = 0; kc < IDIM; kc += 32) {
#pragma unroll
    for (int i = 0; i < 2; ++i) {
      const int f = t + i * 256;
      const int n = f >> 3, j = (f & 7) << 2;
      const float4 v = *(const float4*)(M + (size_t)(n0l + n) * IDIM + kc + j);
      const float4 sv = *(const float4*)(S + (size_t)bglob * IDIM + kc + j);
      const float4 gv = *(const float4*)(GB + kc + j);
      As[(j + 0) * 68 + n] = fmaf(v.x, sv.x, gv.x);
      As[(j + 1) * 68 + n] = fmaf(v.y, sv.y, gv.y);
      As[(j + 2) * 68 + n] = fmaf(v.z, sv.z, gv.z);
      As[(j + 3) * 68 + n] = fmaf(v.w, sv.w, gv.w);
    }
#pragma unroll
    for (int i = 0; i < 2; ++i) {
      const int f = t + i * 256;
      const int k = f >> 4, m4 = (f & 15) << 2;
      *(float4*)(Bs + k * 68 + m4) = *(const float4*)(Wt + (size_t)(kc + k) * CDIM + m0 + m4);
    }
    __syncthreads();
#pragma unroll
    for (int k = 0; k < 32; ++k) {
      const float4 af = *(const float4*)(As + k * 68 + tr * 4);
      const float4 bf = *(const float4*)(Bs + k * 68 + tc * 4);
      const float av[4] = {af.x, af.y, af.z, af.w};
      const float bv[4] = {bf.x, bf.y, bf.z, bf.w};
#pragma unroll
      for (int i = 0; i < 4; ++i)
#pragma unroll
        for (int j = 0; j < 4; ++j) acc[i][j] = fmaf(av[i], bv[j], acc[i][j]);
    }
    __syncthreads();
  }
#pragma unroll
  for (int i = 0; i < 4; ++i) {
    const int ng = n0g + tr * 4 + i;
    const int b = ng >> 12, p = ng & 4095;
#pragma unroll
    for (int j = 0; j < 4; ++j) {
      const int c = m0 + tc * 4 + j;
      const size_t nchw = (((size_t)(b * 256 + c)) << 12) + p;
      const float z = (acc[i][j] + bias[c]) + xin[nchw];
      xout[nchw] = z;
      if (rowsOut) rowsOut[(size_t)ng * 256 + c] = z;
    }
  }
}

// ---------- numpy pairwise sum-of-squares over 256 contiguous floats ----------
__device__ __forceinline__ float np_pairwise_sq_256(const float* p) {
  float half[2];
#pragma unroll
  for (int hh = 0; hh < 2; ++hh) {
    float r[8];
#pragma unroll
    for (int j = 0; j < 8; ++j) {
      const float v = p[hh * 128 + j];
      r[j] = __fmul_rn(v, v);
    }
    for (int i = 8; i < 128; i += 8) {
#pragma unroll
      for (int j = 0; j < 8; ++j) {
        const float v = p[hh * 128 + i + j];
        r[j] = __fadd_rn(r[j], __fmul_rn(v, v));
      }
    }
    half[hh] = __fadd_rn(__fadd_rn(__fadd_rn(r[0], r[1]), __fadd_rn(r[2], r[3])),
                         __fadd_rn(__fadd_rn(r[4], r[5]), __fadd_rn(r[6], r[7])));
  }
  return __fadd_rn(half[0], half[1]);
}

__global__ __launch_bounds__(256) void k_c2(const float* __restrict__ cbk, float* __restrict__ c2) {
  const int k = blockIdx.x * 256 + threadIdx.x;
  c2[k] = np_pairwise_sq_256(cbk + (size_t)k * 256);
}

// ---------- VQ argmin: 64 rows/block in XOR-swizzled LDS, 4 waves x 256 codes ----------
__global__ __launch_bounds__(256) void k_vq(const float* __restrict__ E,
                                            const float* __restrict__ cbk,
                                            const float* __restrict__ c2,
                                            int* __restrict__ idx_i,
                                            float* __restrict__ idx_f) {
  __shared__ float lds[64 * 256];  // phys = elem*64 + (row ^ (elem & 31))
  const int t = threadIdx.x;
  const int n0 = blockIdx.x * 64;
  for (int i = 0; i < 64; ++i) {
    lds[t * 64 + (i ^ (t & 31))] = E[(size_t)(n0 + i) * 256 + t];
  }
  __syncthreads();
  const int w = t >> 6, l = t & 63;
  const int kbase = __builtin_amdgcn_readfirstlane(w) << 8;

  // numpy-pairwise |x|^2 for row l (from swizzled LDS)
  float half[2];
#pragma unroll
  for (int hh = 0; hh < 2; ++hh) {
    float r[8];
#pragma unroll
    for (int j = 0; j < 8; ++j) {
      const int e = hh * 128 + j;
      const float v = lds[e * 64 + (l ^ (e & 31))];
      r[j] = __fmul_rn(v, v);
    }
    for (int i = 8; i < 128; i += 8) {
#pragma unroll
      for (int j = 0; j < 8; ++j) {
        const int e = hh * 128 + i + j;
        const float v = lds[e * 64 + (l ^ (e & 31))];
        r[j] = __fadd_rn(r[j], __fmul_rn(v, v));
      }
    }
    half[hh] = __fadd_rn(__fadd_rn(__fadd_rn(r[0], r[1]), __fadd_rn(r[2], r[3])),
                         __fadd_rn(__fadd_rn(r[4], r[5]), __fadd_rn(r[6], r[7])));
  }
  const float tn = __fadd_rn(half[0], half[1]);

  float best = 3.0e38f;
  int bk = 0;
  for (int kk = 0; kk < 256; kk += 4) {
    const float* cp = cbk + (size_t)(kbase + kk) * 256;
    float a0 = 0.f, a1 = 0.f, a2 = 0.f, a3 = 0.f;
#pragma unroll 8
    for (int e = 0; e < 256; ++e) {
      const float xv = lds[e * 64 + (l ^ (e & 31))];
      a0 = fmaf(xv, cp[e], a0);
      a1 = fmaf(xv, cp[e + 256], a1);
      a2 = fmaf(xv, cp[e + 512], a2);
      a3 = fmaf(xv, cp[e + 768], a3);
    }
    const float d0 = __fadd_rn(__fsub_rn(tn, __fmul_rn(2.0f, a0)), c2[kbase + kk]);
    const float d1 = __fadd_rn(__fsub_rn(tn, __fmul_rn(2.0f, a1)), c2[kbase + kk + 1]);
    const float d2v = __fadd_rn(__fsub_rn(tn, __fmul_rn(2.0f, a2)), c2[kbase + kk + 2]);
    const float d3 = __fadd_rn(__fsub_rn(tn, __fmul_rn(2.0f, a3)), c2[kbase + kk + 3]);
    if (d0 < best) { best = d0; bk = kbase + kk; }
    if (d1 < best) { best = d1; bk = kbase + kk + 1; }
    if (d2v < best) { best = d2v; bk = kbase + kk + 2; }
    if (d3 < best) { best = d3; bk = kbase + kk + 3; }
  }
  __syncthreads();
  lds[w * 64 + l] = best;
  ((int*)lds)[256 + w * 64 + l] = bk;
  __syncthreads();
  if (w == 0) {
    float bv = lds[l];
    int kv = ((int*)lds)[256 + l];
#pragma unroll
    for (int j = 1; j < 4; ++j) {
      const float bj = lds[j * 64 + l];
      const int kj = ((int*)lds)[256 + j * 64 + l];
      if (bj < bv) { bv = bj; kv = kj; }  // ascending k ranges: strict < keeps first min
    }
    idx_i[n0 + l] = kv;
    idx_f[n0 + l] = (float)kv;
  }
}

// ---------- gather codebook rows + STE numerics, write quantized NCHW ----------
__global__ __launch_bounds__(256) void k_gather(const int* __restrict__ idx,
                                                const float* __restrict__ cbk,
                                                const float* __restrict__ E,
                                                float* __restrict__ outq) {
  const int n = blockIdx.x;
  const int c = threadIdx.x;
  const int k = idx[n];
  const float e = E[(size_t)n * 256 + c];
  const float q = __fsub_rn(__fadd_rn(cbk[(size_t)k * 256 + c], e), e);  // (q + x) - x
  const int b = n >> 12, p = n & 4095;
  outq[(((size_t)(b * 256 + c)) << 12) + p] = q;
}

extern "C" void kernel_launch(void* const* d_in, const int* in_sizes, int n_in,
                              void* d_out, int out_size, void* d_ws, size_t ws_size,
                              hipStream_t stream) {
  const float* x = (const float*)d_in[0];
  const float* cbk = (const float*)d_in[1];
  const float* Pe[10];
  const float* Pd[10];
  for (int i = 0; i < 10; ++i) Pe[i] = (const float*)d_in[2 + i];
  for (int i = 0; i < 10; ++i) Pd[i] = (const float*)d_in[12 + i];
  // order: conv_w, conv_b, ln_g, ln_b, fc1_w, fc1_b, grn_g, grn_b, fc2_w, fc2_b

  float* ws = (float*)d_ws;
  size_t off = 0;
  float* R = ws + off;  off += (size_t)NPIX * CDIM;       // NHWC rows (conv/LN)
  float* E = ws + off;  off += (size_t)NPIX * CDIM;       // encoder output rows
  float* P1 = ws + off; off += (size_t)8 * CDIM * HWD;    // NCHW ping buffer
  float* GX = ws + off; off += 8 * IDIM;
  float* S = ws + off;  off += 8 * IDIM;
  float* C2 = ws + off; off += KC;
  int* IDX = (int*)(ws + off); off += NPIX;
  float* M = ws + off;                                    // [chunkB*4096, 1024]
  size_t remain = (ws_size / 4 > off) ? (ws_size / 4 - off) : 0;
  int chunkB = (int)(remain / ((size_t)HWD * IDIM));
  if (chunkB > 8) chunkB = 8;
  if (chunkB < 1) chunkB = 1;

  float* outQ = (float*)d_out;
  float* outD = outQ + (size_t)8 * CDIM * HWD;
  float* outI = outD + (size_t)8 * CDIM * HWD;

  auto run_block = [&](const float* in, float* out, float* rowsOut, const float** pp, int d) {
    k_conv<<<2048, 256, 0, stream>>>(in, pp[0] + (size_t)d * CDIM * 49, pp[1] + d * CDIM, R);
    k_ln<<<NPIX, 256, 0, stream>>>(R, pp[2] + d * CDIM, pp[3] + d * CDIM);
    for (int b0 = 0; b0 < 8; b0 += chunkB) {
      const int nb = (8 - b0 < chunkB) ? (8 - b0) : chunkB;
      const int rows = nb * HWD;
      k_fc1<<<(rows / 64) * 16, 256, 0, stream>>>(R, pp[4] + (size_t)d * CDIM * IDIM,
                                                  pp[5] + d * IDIM, M, b0 * HWD);
      k_grn_reduce<<<nb * 16, 256, 0, stream>>>(M, GX, b0);
      k_grn_scale<<<nb, 256, 0, stream>>>(GX, pp[6] + d * IDIM, S, b0);
      k_fc2<<<(rows / 64) * 4, 256, 0, stream>>>(M, S, pp[7] + d * IDIM,
                                                 pp[8] + (size_t)d * IDIM * CDIM,
                                                 pp[9] + d * CDIM, in, out, rowsOut, b0 * HWD);
    }
  };

  k_c2<<<KC / 256, 256, 0, stream>>>(cbk, C2);
  run_block(x, P1, nullptr, Pe, 0);
  run_block(P1, P1, E, Pe, 1);
  k_vq<<<NPIX / 64, 256, 0, stream>>>(E, cbk, C2, IDX, outI);
  k_gather<<<NPIX, 256, 0, stream>>>(IDX, cbk, E, outQ);
  run_block(outQ, P1, nullptr, Pd, 0);
  run_block(P1, outD, nullptr, Pd, 1);
}

// Round 2
// 1770.470 us; speedup vs baseline: 2.4744x; 2.4744x over previous
//
#include <hip/hip_runtime.h>
#include <math.h>
#include <stdint.h>

typedef unsigned short u16;
typedef unsigned long long u64;
typedef __attribute__((ext_vector_type(8))) short bf16x8;
typedef __attribute__((ext_vector_type(4))) float f32x4;

__device__ __forceinline__ u16 bfhi(float v) {
  unsigned u = __float_as_uint(v);
  u += 0x7FFFu + ((u >> 16) & 1u);
  return (u16)(u >> 16);
}
__device__ __forceinline__ float b2f(u16 h) { return __uint_as_float((unsigned)h << 16); }

__device__ __forceinline__ void gload16(void* lds, const void* g) {
  __builtin_amdgcn_global_load_lds(
      (const __attribute__((address_space(1))) unsigned int*)g,
      (__attribute__((address_space(3))) unsigned int*)lds, 16, 0, 0);
}

// ---------- depthwise conv 7x7 + bias: NCHW -> NHWC rows (16-ch groups) ----------
__global__ __launch_bounds__(256) void k_conv(const float* __restrict__ in,
                                              const float* __restrict__ cw,
                                              const float* __restrict__ cb,
                                              float* __restrict__ rows) {
  const int bx = blockIdx.x;  // 8b * 16ct * 8rt
  const int rt = bx & 7, ct = (bx >> 3) & 15, b = bx >> 7;
  const int c0 = ct * 16, h0 = rt * 8;
  __shared__ float patch[16 * 980];  // 16 ch x 14 x 70
  const int t = threadIdx.x;
  const float* pb = in + ((size_t)(b * 256 + c0)) * 4096;
  for (int i = t; i < 15680; i += 256) {
    const int ch = i / 980, rem = i - ch * 980;
    const int r = rem / 70, cc = rem - r * 70;
    const int h = h0 + r - 3, w = cc - 3;
    float v = 0.f;
    if ((unsigned)h < 64u && (unsigned)w < 64u) v = pb[ch * 4096 + h * 64 + w];
    patch[ch * 980 + rem] = v;
  }
  const int c = t & 15, ps = t >> 4;
  float wt[49];
  const float* wp = cw + (c0 + c) * 49;
#pragma unroll
  for (int i = 0; i < 49; ++i) wt[i] = wp[i];
  const float bias = cb[c0 + c];
  __syncthreads();
  const float* pp = patch + c * 980;
#pragma unroll 1
  for (int g = 0; g < 4; ++g) {
    float acc[8];
#pragma unroll
    for (int u = 0; u < 8; ++u) acc[u] = bias;
#pragma unroll
    for (int kh = 0; kh < 7; ++kh)
#pragma unroll
      for (int kw = 0; kw < 7; ++kw) {
        const float wv = wt[kh * 7 + kw];
#pragma unroll
        for (int u = 0; u < 8; ++u) {
          const int px = ps + 16 * (g * 8 + u);
          acc[u] = fmaf(pp[((px >> 6) + kh) * 70 + (px & 63) + kw], wv, acc[u]);
        }
      }
#pragma unroll
    for (int u = 0; u < 8; ++u) {
      const int px = ps + 16 * (g * 8 + u);
      const int n = (b * 64 + h0 + (px >> 6)) * 64 + (px & 63);
      rows[(size_t)n * 256 + c0 + c] = acc[u];
    }
  }
}

// ---------- LayerNorm over channels -> bf16 hi/lo rows ----------
__global__ __launch_bounds__(256) void k_ln(const float* __restrict__ rows,
                                            const float* __restrict__ g,
                                            const float* __restrict__ bt,
                                            u16* __restrict__ Rh, u16* __restrict__ Rl) {
  const int n = blockIdx.x, t = threadIdx.x;
  const float v = rows[(size_t)n * 256 + t];
  __shared__ float red[4];
  __shared__ float bc;
  const int w = t >> 6, l = t & 63;
  float s = v;
#pragma unroll
  for (int o = 32; o > 0; o >>= 1) s += __shfl_down(s, o);
  if (l == 0) red[w] = s;
  __syncthreads();
  if (t == 0) bc = (red[0] + red[1] + red[2] + red[3]) * (1.0f / 256.0f);
  __syncthreads();
  const float mu = bc;
  const float d = v - mu;
  float s2 = d * d;
#pragma unroll
  for (int o = 32; o > 0; o >>= 1) s2 += __shfl_down(s2, o);
  __syncthreads();
  if (l == 0) red[w] = s2;
  __syncthreads();
  if (t == 0) bc = 1.0f / sqrtf((red[0] + red[1] + red[2] + red[3]) * (1.0f / 256.0f) + 1e-5f);
  __syncthreads();
  const float y = d * bc * g[t] + bt[t];
  const u16 h = bfhi(y);
  Rh[(size_t)n * 256 + t] = h;
  Rl[(size_t)n * 256 + t] = bfhi(y - b2f(h));
}

// ---------- unified MFMA GEMM: C[rows x cols] = sum_terms A_t[rows][K] * B_t[cols][K]^T ----------
// EPI 0: fc1 (+bias, GELU, split->Mh/Ml, GRN sumsq atomics)
// EPI 1: fc2 (+bias2v, +xin NCHW residual, write xout NCHW and/or Eh/El rows)
// EPI 2: vq  (d2 = (tn - 2a) + c2, packed u64 atomicMin per row)
template <int KD, int EPI>
__global__ __launch_bounds__(256) void k_gemm(
    const u16* __restrict__ A0, const u16* __restrict__ A1,
    const u16* __restrict__ B0, const u16* __restrict__ B1,
    const int nt, const int row0, const long long bstride,
    const float* __restrict__ pbias,
    u16* __restrict__ poh, u16* __restrict__ pol,
    float* __restrict__ pxout, const float* __restrict__ pxin_or_tn,
    float* __restrict__ pgx2, u64* __restrict__ pmin) {
  __shared__ u16 As[128 * 64];
  __shared__ u16 Bs[128 * 64];
  const int t = threadIdx.x;
  const int w = t >> 6, l = t & 63;
  const int quad = l >> 4, lm = l & 15;
  const int wr = (w & 1) * 64, wc = (w >> 1) * 64;
  const int colt = blockIdx.x, rowt = blockIdx.y;
  const int nblk0 = rowt * 128;
  const int bglob = (row0 + nblk0) >> 12;
  const u16* Bb0 = B0 + (size_t)bglob * (size_t)bstride;
  const u16* Bb1 = (nt > 2) ? (B1 + (size_t)bglob * (size_t)bstride) : B0;
  f32x4 acc[4][4];
  const f32x4 zz = {0.f, 0.f, 0.f, 0.f};
#pragma unroll
  for (int i = 0; i < 4; ++i)
#pragma unroll
    for (int j = 0; j < 4; ++j) acc[i][j] = zz;

  for (int term = 0; term < nt; ++term) {
    const u16* At = (term == 1) ? A1 : A0;
    const u16* Bt = (term == 2) ? Bb1 : Bb0;
#pragma unroll 1
    for (int ks = 0; ks < KD / 64; ++ks) {
#pragma unroll
      for (int ii = 0; ii < 4; ++ii) {
        const int o = ii * 4096 + t * 16;  // byte offset in 16KB slab
        const int row = o >> 7;
        const int kl = (((o >> 4) & 7) ^ (row & 7)) << 3;  // swizzled source chunk
        gload16((char*)As + o, At + (size_t)(nblk0 + row) * KD + ks * 64 + kl);
      }
#pragma unroll
      for (int ii = 0; ii < 4; ++ii) {
        const int o = ii * 4096 + t * 16;
        const int col = o >> 7;
        const int kl = (((o >> 4) & 7) ^ (col & 7)) << 3;
        gload16((char*)Bs + o, Bt + (size_t)(colt * 128 + col) * KD + ks * 64 + kl);
      }
      __syncthreads();
#pragma unroll
      for (int kk = 0; kk < 2; ++kk) {
        bf16x8 af[4], bfr[4];
#pragma unroll
        for (int i = 0; i < 4; ++i) {
          const int row = wr + i * 16 + lm;
          af[i] = *(const bf16x8*)(As + row * 64 + ((((kk * 4 + quad) ^ (row & 7))) << 3));
          const int col = wc + i * 16 + lm;
          bfr[i] = *(const bf16x8*)(Bs + col * 64 + ((((kk * 4 + quad) ^ (col & 7))) << 3));
        }
#pragma unroll
        for (int i = 0; i < 4; ++i)
#pragma unroll
          for (int j = 0; j < 4; ++j)
            acc[i][j] = __builtin_amdgcn_mfma_f32_16x16x32_bf16(af[i], bfr[j], acc[i][j], 0, 0, 0);
      }
      __syncthreads();
    }
  }

  if constexpr (EPI == 0) {
#pragma unroll
    for (int j = 0; j < 4; ++j) {
      const int col = colt * 128 + wc + j * 16 + lm;
      const float bv = pbias[col];
      float csum = 0.f;
#pragma unroll
      for (int i = 0; i < 4; ++i) {
        const int rb = nblk0 + wr + i * 16 + quad * 4;
#pragma unroll
        for (int r = 0; r < 4; ++r) {
          const float x = acc[i][j][r] + bv;
          const float gl = 0.5f * x * (1.0f + erff(x * 0.70710678118654752f));
          csum = fmaf(gl, gl, csum);
          const size_t idx = (size_t)(rb + r) * 1024 + col;
          const u16 h = bfhi(gl);
          poh[idx] = h;
          if (pol) pol[idx] = bfhi(gl - b2f(h));
        }
      }
      csum += __shfl_xor(csum, 16);
      csum += __shfl_xor(csum, 32);
      if (quad == 0) unsafeAtomicAdd(&pgx2[bglob * 1024 + col], csum);
    }
  } else if constexpr (EPI == 1) {
#pragma unroll
    for (int i = 0; i < 4; ++i) {
      const int nloc = nblk0 + wr + i * 16 + quad * 4;
      const int ng = row0 + nloc;
      const int bb = ng >> 12, p = ng & 4095;
#pragma unroll
      for (int j = 0; j < 4; ++j) {
        const int col = colt * 128 + wc + j * 16 + lm;
        const float bv = pbias[col];
        const size_t nchw = (((size_t)(bb * 256 + col)) << 12) + p;
        const float4 xv = *(const float4*)(pxin_or_tn + nchw);
        float z[4] = {acc[i][j][0] + bv + xv.x, acc[i][j][1] + bv + xv.y,
                      acc[i][j][2] + bv + xv.z, acc[i][j][3] + bv + xv.w};
        if (pxout) {
          float4 ov;
          ov.x = z[0]; ov.y = z[1]; ov.z = z[2]; ov.w = z[3];
          *(float4*)(pxout + nchw) = ov;
        }
        if (poh) {
#pragma unroll
          for (int r = 0; r < 4; ++r) {
            const size_t idx = (size_t)(nloc + r) * 256 + col;
            const u16 h = bfhi(z[r]);
            poh[idx] = h;
            pol[idx] = bfhi(z[r] - b2f(h));
          }
        }
      }
    }
  } else {
#pragma unroll
    for (int i = 0; i < 4; ++i) {
#pragma unroll
      for (int r = 0; r < 4; ++r) {
        const int nloc = nblk0 + wr + i * 16 + quad * 4 + r;
        const float tnv = pxin_or_tn[nloc];
        u64 best = ~0ULL;
#pragma unroll
        for (int j = 0; j < 4; ++j) {
          const int code = colt * 128 + wc + j * 16 + lm;
          const float d = __fadd_rn(__fsub_rn(tnv, __fmul_rn(2.0f, acc[i][j][r])), pbias[code]);
          const u64 pk = (((u64)__float_as_uint(d)) << 32) | (unsigned)code;
          best = pk < best ? pk : best;
        }
#pragma unroll
        for (int off = 1; off < 16; off <<= 1) {
          unsigned lo32 = (unsigned)best, hi32 = (unsigned)(best >> 32);
          lo32 = __shfl_xor(lo32, off);
          hi32 = __shfl_xor(hi32, off);
          const u64 o = (((u64)hi32) << 32) | lo32;
          best = o < best ? o : best;
        }
        if (lm == 0) atomicMin(pmin + nloc, best);
      }
    }
  }
}

// ---------- row sumsq (tn) from bf16 hi/lo E rows ----------
__global__ __launch_bounds__(256) void k_rownorm(const u16* __restrict__ Eh,
                                                 const u16* __restrict__ El,
                                                 float* __restrict__ tn) {
  const int t = threadIdx.x;
  const int r = t >> 2, p = t & 3;
  const int n = blockIdx.x * 64 + r;
  const u16* ph = Eh + (size_t)n * 256 + p * 64;
  const u16* pl = El + (size_t)n * 256 + p * 64;
  float s = 0.f;
#pragma unroll
  for (int j = 0; j < 8; ++j) {
    const uint4 hv = *(const uint4*)(ph + j * 8);
    const uint4 lv = *(const uint4*)(pl + j * 8);
    const unsigned hu[4] = {hv.x, hv.y, hv.z, hv.w};
    const unsigned lu[4] = {lv.x, lv.y, lv.z, lv.w};
#pragma unroll
    for (int q = 0; q < 4; ++q) {
      const float v0 = b2f((u16)(hu[q] & 0xffff)) + b2f((u16)(lu[q] & 0xffff));
      const float v1 = b2f((u16)(hu[q] >> 16)) + b2f((u16)(lu[q] >> 16));
      s = fmaf(v0, v0, s);
      s = fmaf(v1, v1, s);
    }
  }
  s += __shfl_xor(s, 1);
  s += __shfl_xor(s, 2);
  if (p == 0) tn[n] = s;
}

// ---------- GRN scale s = 1 + gg*nx from sumsq ----------
__global__ __launch_bounds__(256) void k_grn_scale(const float* __restrict__ GX2,
                                                   const float* __restrict__ gg,
                                                   float* __restrict__ S, int b0) {
  const int b = b0 + blockIdx.x, t = threadIdx.x;
  const float* gxb = GX2 + (size_t)b * 1024;
  float gx[4];
  float s = 0.f;
#pragma unroll
  for (int i = 0; i < 4; ++i) {
    gx[i] = sqrtf(gxb[t + i * 256]);
    s += gx[i];
  }
  const int w = t >> 6, l = t & 63;
#pragma unroll
  for (int o = 32; o > 0; o >>= 1) s += __shfl_down(s, o);
  __shared__ float red[4];
  __shared__ float bc;
  if (l == 0) red[w] = s;
  __syncthreads();
  if (t == 0) bc = 1.0f / ((red[0] + red[1] + red[2] + red[3]) * (1.0f / 1024.0f) + 1e-6f);
  __syncthreads();
  const float inv = bc;
#pragma unroll
  for (int i = 0; i < 4; ++i)
    S[(size_t)b * 1024 + t + i * 256] = fmaf(gg[t + i * 256], gx[i] * inv, 1.0f);
}

// ---------- per-batch scaled+split+transposed W2 ----------
__global__ __launch_bounds__(256) void k_w2prep(const float* __restrict__ W2,
                                                const float* __restrict__ S, int b0,
                                                u16* __restrict__ Wh, u16* __restrict__ Wl) {
  const int bx = blockIdx.x;
  const int b = b0 + (bx >> 8), n = bx & 255;
  const int t = threadIdx.x;
#pragma unroll
  for (int j = 0; j < 4; ++j) {
    const int k = t + j * 256;
    const float v = W2[(size_t)k * 256 + n] * S[(size_t)b * 1024 + k];
    const size_t idx = ((size_t)(b * 256 + n)) * 1024 + k;
    const u16 h = bfhi(v);
    Wh[idx] = h;
    Wl[idx] = bfhi(v - b2f(h));
  }
}

// ---------- bias2v = b2 + gb @ W2 ----------
__global__ __launch_bounds__(256) void k_bias2(const float* __restrict__ W2,
                                               const float* __restrict__ gb,
                                               const float* __restrict__ b2,
                                               float* __restrict__ out) {
  const int c = threadIdx.x;
  float acc = b2[c];
  for (int k = 0; k < 1024; ++k) acc = fmaf(gb[k], W2[(size_t)k * 256 + c], acc);
  out[c] = acc;
}

// ---------- W1^T split ----------
__global__ __launch_bounds__(256) void k_wt(const float* __restrict__ W1,
                                            u16* __restrict__ Wh, u16* __restrict__ Wl) {
  const int bx = blockIdx.x;  // d*1024 + n
  const int d = bx >> 10, n = bx & 1023;
  const int k = threadIdx.x;
  const float v = W1[(size_t)d * 262144 + (size_t)k * 1024 + n];
  const size_t idx = (size_t)bx * 256 + k;
  const u16 h = bfhi(v);
  Wh[idx] = h;
  Wl[idx] = bfhi(v - b2f(h));
}

// ---------- codebook split ----------
__global__ __launch_bounds__(256) void k_csplit(const float* __restrict__ C,
                                                u16* __restrict__ Ch, u16* __restrict__ Cl) {
  const size_t i = (size_t)blockIdx.x * 256 + threadIdx.x;
  const float v = C[i];
  const u16 h = bfhi(v);
  Ch[i] = h;
  Cl[i] = bfhi(v - b2f(h));
}

// ---------- numpy-pairwise |c|^2 per code ----------
__device__ __forceinline__ float np_pairwise_sq_256(const float* p) {
  float half[2];
#pragma unroll
  for (int hh = 0; hh < 2; ++hh) {
    float r[8];
#pragma unroll
    for (int j = 0; j < 8; ++j) {
      const float v = p[hh * 128 + j];
      r[j] = __fmul_rn(v, v);
    }
    for (int i = 8; i < 128; i += 8) {
#pragma unroll
      for (int j = 0; j < 8; ++j) {
        const float v = p[hh * 128 + i + j];
        r[j] = __fadd_rn(r[j], __fmul_rn(v, v));
      }
    }
    half[hh] = __fadd_rn(__fadd_rn(__fadd_rn(r[0], r[1]), __fadd_rn(r[2], r[3])),
                         __fadd_rn(__fadd_rn(r[4], r[5]), __fadd_rn(r[6], r[7])));
  }
  return __fadd_rn(half[0], half[1]);
}

__global__ __launch_bounds__(256) void k_c2(const float* __restrict__ cbk, float* __restrict__ c2) {
  const int k = blockIdx.x * 256 + threadIdx.x;
  c2[k] = np_pairwise_sq_256(cbk + (size_t)k * 256);
}

// ---------- index output + quantized gather ----------
__global__ __launch_bounds__(256) void k_idx(const u64* __restrict__ pk, float* __restrict__ outI) {
  const int n = blockIdx.x * 256 + threadIdx.x;
  outI[n] = (float)(unsigned)(pk[n] & 0xffffffffULL);
}

__global__ __launch_bounds__(256) void k_gather(const u64* __restrict__ pk,
                                                const float* __restrict__ cbk,
                                                float* __restrict__ outq) {
  const int bx = blockIdx.x;  // b*256 + c
  const int b = bx >> 8, c = bx & 255;
  const int t = threadIdx.x;
#pragma unroll 1
  for (int j = 0; j < 16; ++j) {
    const int p = t + j * 256;
    const int k = (int)(unsigned)(pk[b * 4096 + p] & 0xffffffffULL);
    outq[(((size_t)(b * 256 + c)) << 12) + p] = cbk[(size_t)k * 256 + c];
  }
}

extern "C" void kernel_launch(void* const* d_in, const int* in_sizes, int n_in,
                              void* d_out, int out_size, void* d_ws, size_t ws_size,
                              hipStream_t stream) {
  const float* x = (const float*)d_in[0];
  const float* cbk = (const float*)d_in[1];
  const float* Pe[10];
  const float* Pd[10];
  for (int i = 0; i < 10; ++i) Pe[i] = (const float*)d_in[2 + i];
  for (int i = 0; i < 10; ++i) Pd[i] = (const float*)d_in[12 + i];
  // order per dict: conv_w, conv_b, ln_g, ln_b, fc1_w, fc1_b, grn_g, grn_b, fc2_w, fc2_b

  float* ws = (float*)d_ws;
  size_t o = 0;
  auto alloc = [&](size_t nf) {
    float* p = ws + o;
    o += (nf + 63) & ~(size_t)63;
    return p;
  };
  float* P1 = alloc(8388608);                   // NCHW ping
  u16* Rh = (u16*)alloc(4194304);               // rows hi (also E hi)
  u16* Rl = (u16*)alloc(4194304);               // rows lo (also E lo)
  u16* W1th_e = (u16*)alloc(262144);
  u16* W1tl_e = (u16*)alloc(262144);
  u16* W1th_d = (u16*)alloc(262144);
  u16* W1tl_d = (u16*)alloc(262144);
  u16* W2sh = (u16*)alloc(1048576);
  u16* W2sl = (u16*)alloc(1048576);
  u16* Ch = (u16*)alloc(131072);
  u16* Cl = (u16*)alloc(131072);
  float* C2v = alloc(1024);
  float* GX2 = alloc(8192);
  float* Sv = alloc(8192);
  float* bias2v = alloc(256);
  float* tn = alloc(32768);
  u64* pk = (u64*)alloc(65536);
  const size_t fixedf = o;
  const size_t availf = (ws_size / 4 > fixedf) ? ws_size / 4 - fixedf : 0;
  int chunkB = (int)(availf / 4194304);  // Mh+Ml per batch = 4M floats worth
  if (chunkB > 8) chunkB = 8;
  if (chunkB < 1) chunkB = 1;
  float* R = ws + o;       // fp32 conv rows, aliases M arena (dead by fc1 time)
  u16* Mh = (u16*)(ws + o);
  u16* Ml = (u16*)(ws + o + (size_t)chunkB * 2097152);

  float* outQ = (float*)d_out;
  float* outD = outQ + 8388608;
  float* outI = outD + 8388608;

  auto run_block = [&](const float* xin, float* xout, u16* Eh, u16* El,
                       const float* const* pp, int d, int nt,
                       const u16* w1h, const u16* w1l) {
    k_conv<<<1024, 256, 0, stream>>>(xin, pp[0] + (size_t)d * 256 * 49, pp[1] + d * 256, R);
    k_ln<<<32768, 256, 0, stream>>>(R, pp[2] + d * 256, pp[3] + d * 256, Rh, Rl);
    k_bias2<<<1, 256, 0, stream>>>(pp[8] + (size_t)d * 262144, pp[7] + d * 1024,
                                   pp[9] + d * 256, bias2v);
    hipMemsetAsync(GX2, 0, 8192 * 4, stream);
    for (int b0 = 0; b0 < 8; b0 += chunkB) {
      const int nb = (8 - b0 < chunkB) ? 8 - b0 : chunkB;
      k_gemm<256, 0><<<dim3(8, nb * 32), 256, 0, stream>>>(
          Rh + (size_t)b0 * 4096 * 256, Rl + (size_t)b0 * 4096 * 256,
          w1h + (size_t)d * 262144, w1l + (size_t)d * 262144,
          nt, b0 * 4096, 0,
          pp[5] + d * 1024, Mh, (nt == 3) ? Ml : (u16*)nullptr,
          nullptr, nullptr, GX2, nullptr);
      k_grn_scale<<<nb, 256, 0, stream>>>(GX2, pp[6] + d * 1024, Sv, b0);
      k_w2prep<<<nb * 256, 256, 0, stream>>>(pp[8] + (size_t)d * 262144, Sv, b0, W2sh, W2sl);
      k_gemm<1024, 1><<<dim3(2, nb * 32), 256, 0, stream>>>(
          Mh, Ml, W2sh, W2sl, nt, b0 * 4096, 262144LL,
          bias2v,
          Eh ? Eh + (size_t)b0 * 4096 * 256 : (u16*)nullptr,
          El ? El + (size_t)b0 * 4096 * 256 : (u16*)nullptr,
          xout, xin, nullptr, nullptr);
    }
  };

  // prep
  k_wt<<<2048, 256, 0, stream>>>(Pe[4], W1th_e, W1tl_e);
  k_wt<<<2048, 256, 0, stream>>>(Pd[4], W1th_d, W1tl_d);
  k_csplit<<<1024, 256, 0, stream>>>(cbk, Ch, Cl);
  k_c2<<<4, 256, 0, stream>>>(cbk, C2v);

  // encoder (split-bf16, 3 terms)
  run_block(x, P1, nullptr, nullptr, Pe, 0, 3, W1th_e, W1tl_e);
  run_block(P1, nullptr, Rh, Rl, Pe, 1, 3, W1th_e, W1tl_e);  // E -> Rh/Rl, no NCHW out

  // VQ
  k_rownorm<<<512, 256, 0, stream>>>(Rh, Rl, tn);
  hipMemsetAsync(pk, 0xFF, 32768 * 8, stream);
  k_gemm<256, 2><<<dim3(8, 256), 256, 0, stream>>>(Rh, Rl, Ch, Cl, 3, 0, 0,
                                                   C2v, nullptr, nullptr, nullptr, tn,
                                                   nullptr, pk);
  k_idx<<<128, 256, 0, stream>>>(pk, outI);
  k_gather<<<2048, 256, 0, stream>>>(pk, cbk, outQ);

  // decoder (plain bf16, 1 term)
  run_block(outQ, P1, nullptr, nullptr, Pd, 0, 1, W1th_d, W1tl_d);
  run_block(P1, outD, nullptr, nullptr, Pd, 1, 1, W1th_d, W1tl_d);
}

// Round 3
// 1545.882 us; speedup vs baseline: 2.8339x; 1.1453x over previous
//
#include <hip/hip_runtime.h>
#include <math.h>
#include <stdint.h>

typedef unsigned short u16;
typedef unsigned long long u64;
typedef __attribute__((ext_vector_type(8))) short bf16x8;
typedef __attribute__((ext_vector_type(4))) float f32x4;

__device__ __forceinline__ u16 bfhi(float v) {
  unsigned u = __float_as_uint(v);
  u += 0x7FFFu + ((u >> 16) & 1u);
  return (u16)(u >> 16);
}
__device__ __forceinline__ float b2f(u16 h) { return __uint_as_float((unsigned)h << 16); }

__device__ __forceinline__ void gload16(void* lds, const void* g) {
  __builtin_amdgcn_global_load_lds(
      (const __attribute__((address_space(1))) unsigned int*)g,
      (__attribute__((address_space(3))) unsigned int*)lds, 16, 0, 0);
}

// ---------- depthwise conv 7x7 + bias: NCHW -> NHWC rows (16-ch groups) ----------
__global__ __launch_bounds__(256) void k_conv(const float* __restrict__ in,
                                              const float* __restrict__ cw,
                                              const float* __restrict__ cb,
                                              float* __restrict__ rows) {
  const int bx = blockIdx.x;  // 8b * 16ct * 8rt
  const int rt = bx & 7, ct = (bx >> 3) & 15, b = bx >> 7;
  const int c0 = ct * 16, h0 = rt * 8;
  __shared__ float patch[16 * 980];  // 16 ch x 14 x 70
  const int t = threadIdx.x;
  const float* pb = in + ((size_t)(b * 256 + c0)) * 4096;
  for (int i = t; i < 15680; i += 256) {
    const int ch = i / 980, rem = i - ch * 980;
    const int r = rem / 70, cc = rem - r * 70;
    const int h = h0 + r - 3, w = cc - 3;
    float v = 0.f;
    if ((unsigned)h < 64u && (unsigned)w < 64u) v = pb[ch * 4096 + h * 64 + w];
    patch[ch * 980 + rem] = v;
  }
  const int c = t & 15, ps = t >> 4;
  float wt[49];
  const float* wp = cw + (c0 + c) * 49;
#pragma unroll
  for (int i = 0; i < 49; ++i) wt[i] = wp[i];
  const float bias = cb[c0 + c];
  __syncthreads();
  const float* pp = patch + c * 980;
#pragma unroll 1
  for (int g = 0; g < 4; ++g) {
    float acc[8];
#pragma unroll
    for (int u = 0; u < 8; ++u) acc[u] = bias;
#pragma unroll
    for (int kh = 0; kh < 7; ++kh)
#pragma unroll
      for (int kw = 0; kw < 7; ++kw) {
        const float wv = wt[kh * 7 + kw];
#pragma unroll
        for (int u = 0; u < 8; ++u) {
          const int px = ps + 16 * (g * 8 + u);
          acc[u] = fmaf(pp[((px >> 6) + kh) * 70 + (px & 63) + kw], wv, acc[u]);
        }
      }
#pragma unroll
    for (int u = 0; u < 8; ++u) {
      const int px = ps + 16 * (g * 8 + u);
      const int n = (b * 64 + h0 + (px >> 6)) * 64 + (px & 63);
      rows[(size_t)n * 256 + c0 + c] = acc[u];
    }
  }
}

// ---------- LayerNorm over channels -> bf16 hi/lo rows ----------
__global__ __launch_bounds__(256) void k_ln(const float* __restrict__ rows,
                                            const float* __restrict__ g,
                                            const float* __restrict__ bt,
                                            u16* __restrict__ Rh, u16* __restrict__ Rl) {
  const int n = blockIdx.x, t = threadIdx.x;
  const float v = rows[(size_t)n * 256 + t];
  __shared__ float red[4];
  __shared__ float bc;
  const int w = t >> 6, l = t & 63;
  float s = v;
#pragma unroll
  for (int o = 32; o > 0; o >>= 1) s += __shfl_down(s, o);
  if (l == 0) red[w] = s;
  __syncthreads();
  if (t == 0) bc = (red[0] + red[1] + red[2] + red[3]) * (1.0f / 256.0f);
  __syncthreads();
  const float mu = bc;
  const float d = v - mu;
  float s2 = d * d;
#pragma unroll
  for (int o = 32; o > 0; o >>= 1) s2 += __shfl_down(s2, o);
  __syncthreads();
  if (l == 0) red[w] = s2;
  __syncthreads();
  if (t == 0) bc = 1.0f / sqrtf((red[0] + red[1] + red[2] + red[3]) * (1.0f / 256.0f) + 1e-5f);
  __syncthreads();
  const float y = d * bc * g[t] + bt[t];
  const u16 h = bfhi(y);
  Rh[(size_t)n * 256 + t] = h;
  Rl[(size_t)n * 256 + t] = bfhi(y - b2f(h));
}

// ---------- fused-term MFMA GEMM: C = (Ah+Al) * (Bh+Bl)^T (drop lo*lo) ----------
// EPI 0: fc1 (+bias, GELU, split->Mh/Ml, GRN sumsq atomics)
// EPI 1: fc2 (+bias, +xin NCHW residual via LDS transpose; xout NCHW and/or Eh/El rows)
// EPI 2: vq  (d2 = (tn - 2a) + c2, packed u64 atomicMin per row)
template <int KD, int SPLIT, int EPI>
__global__ __launch_bounds__(256) void k_gemm(
    const u16* __restrict__ Ah_, const u16* __restrict__ Al_,
    const u16* __restrict__ Bh_, const u16* __restrict__ Bl_,
    const int row0, const long long bstride,
    const float* __restrict__ pbias,
    u16* __restrict__ poh, u16* __restrict__ pol,
    float* __restrict__ pxout, const float* __restrict__ pxin,
    float* __restrict__ pgx2, u64* __restrict__ pmin) {
  constexpr int STAGE_B = (SPLIT ? 4 : 2) * 16384;
  constexpr int TRANS_B = (EPI == 1) ? 64 * 129 * 4 : 0;
  constexpr int SMEM_B = STAGE_B > TRANS_B ? STAGE_B : TRANS_B;
  __shared__ __align__(16) char smem[SMEM_B];
  u16* As_h = (u16*)smem;
  u16* As_l = (u16*)(smem + 16384);
  u16* Bs_h = (u16*)(smem + (SPLIT ? 32768 : 16384));
  u16* Bs_l = (u16*)(smem + 49152);

  const int t = threadIdx.x;
  const int w = t >> 6, l = t & 63;
  const int quad = l >> 4, lm = l & 15;
  const int wr = (w & 1) * 64, wc = (w >> 1) * 64;
  const int colt = blockIdx.x, rowt = blockIdx.y;
  const int nblk0 = rowt * 128;
  const int bglob = (row0 + nblk0) >> 12;

  const u16* Agh = Ah_ + (size_t)nblk0 * KD;
  const u16* Agl = SPLIT ? (Al_ + (size_t)nblk0 * KD) : Ah_;
  const u16* Bgh = Bh_ + (size_t)bglob * (size_t)bstride + (size_t)(colt * 128) * KD;
  const u16* Bgl = SPLIT ? (Bl_ + (size_t)bglob * (size_t)bstride + (size_t)(colt * 128) * KD) : Bh_;

  f32x4 acc[4][4];
  const f32x4 zz = {0.f, 0.f, 0.f, 0.f};
#pragma unroll
  for (int i = 0; i < 4; ++i)
#pragma unroll
    for (int j = 0; j < 4; ++j) acc[i][j] = zz;

  auto stage = [&](u16* Sp, const u16* Gp, int ks) {
#pragma unroll
    for (int ii = 0; ii < 4; ++ii) {
      const int o = ii * 4096 + t * 16;  // byte offset in 16KB slab
      const int row = o >> 7;
      const int kl = (((o >> 4) & 7) ^ (row & 7)) << 3;  // swizzled source chunk
      gload16((char*)Sp + o, Gp + (size_t)row * KD + ks * 64 + kl);
    }
  };

#pragma unroll 1
  for (int ks = 0; ks < KD / 64; ++ks) {
    stage(As_h, Agh, ks);
    stage(Bs_h, Bgh, ks);
    if constexpr (SPLIT) {
      stage(As_l, Agl, ks);
      stage(Bs_l, Bgl, ks);
    }
    __syncthreads();
#pragma unroll
    for (int kk = 0; kk < 2; ++kk) {
      bf16x8 ah[4], bh[4];
#pragma unroll
      for (int i = 0; i < 4; ++i) {
        const int row = wr + i * 16 + lm;
        ah[i] = *(const bf16x8*)(As_h + row * 64 + (((kk * 4 + quad) ^ (row & 7)) << 3));
        const int col = wc + i * 16 + lm;
        bh[i] = *(const bf16x8*)(Bs_h + col * 64 + (((kk * 4 + quad) ^ (col & 7)) << 3));
      }
#pragma unroll
      for (int i = 0; i < 4; ++i)
#pragma unroll
        for (int j = 0; j < 4; ++j)
          acc[i][j] = __builtin_amdgcn_mfma_f32_16x16x32_bf16(ah[i], bh[j], acc[i][j], 0, 0, 0);
      if constexpr (SPLIT) {
        bf16x8 xl[4];
#pragma unroll
        for (int i = 0; i < 4; ++i) {
          const int row = wr + i * 16 + lm;
          xl[i] = *(const bf16x8*)(As_l + row * 64 + (((kk * 4 + quad) ^ (row & 7)) << 3));
        }
#pragma unroll
        for (int i = 0; i < 4; ++i)
#pragma unroll
          for (int j = 0; j < 4; ++j)
            acc[i][j] = __builtin_amdgcn_mfma_f32_16x16x32_bf16(xl[i], bh[j], acc[i][j], 0, 0, 0);
#pragma unroll
        for (int i = 0; i < 4; ++i) {
          const int col = wc + i * 16 + lm;
          xl[i] = *(const bf16x8*)(Bs_l + col * 64 + (((kk * 4 + quad) ^ (col & 7)) << 3));
        }
#pragma unroll
        for (int i = 0; i < 4; ++i)
#pragma unroll
          for (int j = 0; j < 4; ++j)
            acc[i][j] = __builtin_amdgcn_mfma_f32_16x16x32_bf16(ah[i], xl[j], acc[i][j], 0, 0, 0);
      }
    }
    __syncthreads();
  }

  if constexpr (EPI == 0) {
    float csum[4] = {0.f, 0.f, 0.f, 0.f};
    float bv[4];
#pragma unroll
    for (int j = 0; j < 4; ++j) bv[j] = pbias[colt * 128 + wc + j * 16 + lm];
#pragma unroll
    for (int i = 0; i < 4; ++i) {
#pragma unroll
      for (int r = 0; r < 4; ++r) {
        const int row = nblk0 + wr + i * 16 + quad * 4 + r;
#pragma unroll
        for (int j = 0; j < 4; ++j) {
          const int col = colt * 128 + wc + j * 16 + lm;
          const float x = acc[i][j][r] + bv[j];
          const float gl = 0.5f * x * (1.0f + erff(x * 0.70710678118654752f));
          csum[j] = fmaf(gl, gl, csum[j]);
          const size_t idx = (size_t)row * 1024 + col;
          const u16 h = bfhi(gl);
          poh[idx] = h;
          if constexpr (SPLIT) pol[idx] = bfhi(gl - b2f(h));
        }
      }
    }
#pragma unroll
    for (int j = 0; j < 4; ++j) {
      float cs = csum[j];
      cs += __shfl_xor(cs, 16);
      cs += __shfl_xor(cs, 32);
      if (quad == 0)
        unsafeAtomicAdd(&pgx2[bglob * 1024 + colt * 128 + wc + j * 16 + lm], cs);
    }
  } else if constexpr (EPI == 1) {
    float* T = (float*)smem;  // [64 cols][pitch 129] f32, per col-half
    const int pg0 = (row0 + nblk0) & 4095;
    const int bb = (row0 + nblk0) >> 12;
#pragma unroll 1
    for (int h = 0; h < 2; ++h) {
      __syncthreads();
      if ((w >> 1) == h) {
#pragma unroll
        for (int i = 0; i < 4; ++i) {
          const int row = wr + i * 16 + quad * 4;
#pragma unroll
          for (int j = 0; j < 4; ++j) {
            const int cl = j * 16 + lm;
#pragma unroll
            for (int r = 0; r < 4; ++r) T[cl * 129 + row + r] = acc[i][j][r];
          }
        }
      }
      __syncthreads();
      const int lp = (l & 31) * 4;
      const int ch2 = l >> 5;
#pragma unroll
      for (int step = 0; step < 8; ++step) {
        const int cl = w * 16 + step * 2 + ch2;
        const int cg = colt * 128 + h * 64 + cl;
        float4 tv = *(float4*)&T[cl * 129 + lp];
        const float bv2 = pbias[cg];
        const size_t nchw = (((size_t)(bb * 256 + cg)) << 12) + pg0 + lp;
        const float4 xv = *(const float4*)(pxin + nchw);
        float4 z;
        z.x = tv.x + bv2 + xv.x;
        z.y = tv.y + bv2 + xv.y;
        z.z = tv.z + bv2 + xv.z;
        z.w = tv.w + bv2 + xv.w;
        if (pxout) *(float4*)(pxout + nchw) = z;
        if (poh) *(float4*)&T[cl * 129 + lp] = z;
      }
      if (poh) {
        __syncthreads();
        const int cl3 = t & 63;
        const int cg3 = colt * 128 + h * 64 + cl3;
        const int r0 = (t >> 6) * 32;
#pragma unroll
        for (int n = 0; n < 32; ++n) {
          const float z = T[cl3 * 129 + r0 + n];
          const size_t idx = (size_t)(nblk0 + r0 + n) * 256 + cg3;
          const u16 hh = bfhi(z);
          poh[idx] = hh;
          pol[idx] = bfhi(z - b2f(hh));
        }
      }
    }
  } else {
#pragma unroll
    for (int i = 0; i < 4; ++i) {
#pragma unroll
      for (int r = 0; r < 4; ++r) {
        const int nloc = nblk0 + wr + i * 16 + quad * 4 + r;
        const float tnv = pxin[nloc];
        u64 best = ~0ULL;
#pragma unroll
        for (int j = 0; j < 4; ++j) {
          const int code = colt * 128 + wc + j * 16 + lm;
          const float d = __fadd_rn(__fsub_rn(tnv, __fmul_rn(2.0f, acc[i][j][r])), pbias[code]);
          const u64 pk = (((u64)__float_as_uint(d)) << 32) | (unsigned)code;
          best = pk < best ? pk : best;
        }
#pragma unroll
        for (int off = 1; off < 16; off <<= 1) {
          unsigned lo32 = (unsigned)best, hi32 = (unsigned)(best >> 32);
          lo32 = __shfl_xor(lo32, off);
          hi32 = __shfl_xor(hi32, off);
          const u64 o2 = (((u64)hi32) << 32) | lo32;
          best = o2 < best ? o2 : best;
        }
        if (lm == 0) atomicMin(pmin + nloc, best);
      }
    }
  }
}

// ---------- row sumsq (tn) from bf16 hi/lo E rows ----------
__global__ __launch_bounds__(256) void k_rownorm(const u16* __restrict__ Eh,
                                                 const u16* __restrict__ El,
                                                 float* __restrict__ tn) {
  const int t = threadIdx.x;
  const int r = t >> 2, p = t & 3;
  const int n = blockIdx.x * 64 + r;
  const u16* ph = Eh + (size_t)n * 256 + p * 64;
  const u16* pl = El + (size_t)n * 256 + p * 64;
  float s = 0.f;
#pragma unroll
  for (int j = 0; j < 8; ++j) {
    const uint4 hv = *(const uint4*)(ph + j * 8);
    const uint4 lv = *(const uint4*)(pl + j * 8);
    const unsigned hu[4] = {hv.x, hv.y, hv.z, hv.w};
    const unsigned lu[4] = {lv.x, lv.y, lv.z, lv.w};
#pragma unroll
    for (int q = 0; q < 4; ++q) {
      const float v0 = b2f((u16)(hu[q] & 0xffff)) + b2f((u16)(lu[q] & 0xffff));
      const float v1 = b2f((u16)(hu[q] >> 16)) + b2f((u16)(lu[q] >> 16));
      s = fmaf(v0, v0, s);
      s = fmaf(v1, v1, s);
    }
  }
  s += __shfl_xor(s, 1);
  s += __shfl_xor(s, 2);
  if (p == 0) tn[n] = s;
}

// ---------- GRN scale s = 1 + gg*nx from sumsq ----------
__global__ __launch_bounds__(256) void k_grn_scale(const float* __restrict__ GX2,
                                                   const float* __restrict__ gg,
                                                   float* __restrict__ S, int b0) {
  const int b = b0 + blockIdx.x, t = threadIdx.x;
  const float* gxb = GX2 + (size_t)b * 1024;
  float gx[4];
  float s = 0.f;
#pragma unroll
  for (int i = 0; i < 4; ++i) {
    gx[i] = sqrtf(gxb[t + i * 256]);
    s += gx[i];
  }
  const int w = t >> 6, l = t & 63;
#pragma unroll
  for (int o = 32; o > 0; o >>= 1) s += __shfl_down(s, o);
  __shared__ float red[4];
  __shared__ float bc;
  if (l == 0) red[w] = s;
  __syncthreads();
  if (t == 0) bc = 1.0f / ((red[0] + red[1] + red[2] + red[3]) * (1.0f / 1024.0f) + 1e-6f);
  __syncthreads();
  const float inv = bc;
#pragma unroll
  for (int i = 0; i < 4; ++i)
    S[(size_t)b * 1024 + t + i * 256] = fmaf(gg[t + i * 256], gx[i] * inv, 1.0f);
}

// ---------- per-batch scaled+split+transposed W2 ----------
__global__ __launch_bounds__(256) void k_w2prep(const float* __restrict__ W2,
                                                const float* __restrict__ S, int b0,
                                                u16* __restrict__ Wh, u16* __restrict__ Wl) {
  const int bx = blockIdx.x;
  const int b = b0 + (bx >> 8), n = bx & 255;
  const int t = threadIdx.x;
#pragma unroll
  for (int j = 0; j < 4; ++j) {
    const int k = t + j * 256;
    const float v = W2[(size_t)k * 256 + n] * S[(size_t)b * 1024 + k];
    const size_t idx = ((size_t)(b * 256 + n)) * 1024 + k;
    const u16 h = bfhi(v);
    Wh[idx] = h;
    Wl[idx] = bfhi(v - b2f(h));
  }
}

// ---------- bias2v = b2 + gb @ W2 (one block per output channel) ----------
__global__ __launch_bounds__(256) void k_bias2(const float* __restrict__ W2,
                                               const float* __restrict__ gb,
                                               const float* __restrict__ b2,
                                               float* __restrict__ out) {
  const int c = blockIdx.x, t = threadIdx.x;
  float acc = 0.f;
#pragma unroll
  for (int j = 0; j < 4; ++j) {
    const int k = t + j * 256;
    acc = fmaf(gb[k], W2[(size_t)k * 256 + c], acc);
  }
  const int w = t >> 6, l = t & 63;
#pragma unroll
  for (int o = 32; o > 0; o >>= 1) acc += __shfl_down(acc, o);
  __shared__ float red[4];
  if (l == 0) red[w] = acc;
  __syncthreads();
  if (t == 0) out[c] = red[0] + red[1] + red[2] + red[3] + b2[c];
}

// ---------- W1^T split ----------
__global__ __launch_bounds__(256) void k_wt(const float* __restrict__ W1,
                                            u16* __restrict__ Wh, u16* __restrict__ Wl) {
  const int bx = blockIdx.x;  // d*1024 + n
  const int d = bx >> 10, n = bx & 1023;
  const int k = threadIdx.x;
  const float v = W1[(size_t)d * 262144 + (size_t)k * 1024 + n];
  const size_t idx = (size_t)bx * 256 + k;
  const u16 h = bfhi(v);
  Wh[idx] = h;
  Wl[idx] = bfhi(v - b2f(h));
}

// ---------- codebook split ----------
__global__ __launch_bounds__(256) void k_csplit(const float* __restrict__ C,
                                                u16* __restrict__ Ch, u16* __restrict__ Cl) {
  const size_t i = (size_t)blockIdx.x * 256 + threadIdx.x;
  const float v = C[i];
  const u16 h = bfhi(v);
  Ch[i] = h;
  Cl[i] = bfhi(v - b2f(h));
}

// ---------- numpy-pairwise |c|^2 per code ----------
__device__ __forceinline__ float np_pairwise_sq_256(const float* p) {
  float half[2];
#pragma unroll
  for (int hh = 0; hh < 2; ++hh) {
    float r[8];
#pragma unroll
    for (int j = 0; j < 8; ++j) {
      const float v = p[hh * 128 + j];
      r[j] = __fmul_rn(v, v);
    }
    for (int i = 8; i < 128; i += 8) {
#pragma unroll
      for (int j = 0; j < 8; ++j) {
        const float v = p[hh * 128 + i + j];
        r[j] = __fadd_rn(r[j], __fmul_rn(v, v));
      }
    }
    half[hh] = __fadd_rn(__fadd_rn(__fadd_rn(r[0], r[1]), __fadd_rn(r[2], r[3])),
                         __fadd_rn(__fadd_rn(r[4], r[5]), __fadd_rn(r[6], r[7])));
  }
  return __fadd_rn(half[0], half[1]);
}

__global__ __launch_bounds__(256) void k_c2(const float* __restrict__ cbk, float* __restrict__ c2) {
  const int k = blockIdx.x * 256 + threadIdx.x;
  c2[k] = np_pairwise_sq_256(cbk + (size_t)k * 256);
}

// ---------- index output + quantized gather ----------
__global__ __launch_bounds__(256) void k_idx(const u64* __restrict__ pk, float* __restrict__ outI) {
  const int n = blockIdx.x * 256 + threadIdx.x;
  outI[n] = (float)(unsigned)(pk[n] & 0xffffffffULL);
}

__global__ __launch_bounds__(256) void k_gather(const u64* __restrict__ pk,
                                                const float* __restrict__ cbk,
                                                float* __restrict__ outq) {
  const int bx = blockIdx.x;  // b*256 + c
  const int b = bx >> 8, c = bx & 255;
  const int t = threadIdx.x;
#pragma unroll 1
  for (int j = 0; j < 16; ++j) {
    const int p = t + j * 256;
    const int k = (int)(unsigned)(pk[b * 4096 + p] & 0xffffffffULL);
    outq[(((size_t)(b * 256 + c)) << 12) + p] = cbk[(size_t)k * 256 + c];
  }
}

extern "C" void kernel_launch(void* const* d_in, const int* in_sizes, int n_in,
                              void* d_out, int out_size, void* d_ws, size_t ws_size,
                              hipStream_t stream) {
  const float* x = (const float*)d_in[0];
  const float* cbk = (const float*)d_in[1];
  const float* Pe[10];
  const float* Pd[10];
  for (int i = 0; i < 10; ++i) Pe[i] = (const float*)d_in[2 + i];
  for (int i = 0; i < 10; ++i) Pd[i] = (const float*)d_in[12 + i];
  // order per dict: conv_w, conv_b, ln_g, ln_b, fc1_w, fc1_b, grn_g, grn_b, fc2_w, fc2_b

  float* ws = (float*)d_ws;
  size_t o = 0;
  auto alloc = [&](size_t nf) {
    float* p = ws + o;
    o += (nf + 63) & ~(size_t)63;
    return p;
  };
  float* P1 = alloc(8388608);      // NCHW ping
  u16* Rh = (u16*)alloc(4194304);  // rows hi (also E hi)
  u16* Rl = (u16*)alloc(4194304);  // rows lo (also E lo)
  u16* W1th_e = (u16*)alloc(262144);
  u16* W1tl_e = (u16*)alloc(262144);
  u16* W1th_d = (u16*)alloc(262144);
  u16* W1tl_d = (u16*)alloc(262144);
  u16* W2sh = (u16*)alloc(1048576);
  u16* W2sl = (u16*)alloc(1048576);
  u16* Ch = (u16*)alloc(131072);
  u16* Cl = (u16*)alloc(131072);
  float* C2v = alloc(1024);
  float* GX2 = alloc(8192);
  float* Sv = alloc(8192);
  float* bias2v = alloc(256);
  float* tn = alloc(32768);
  u64* pk = (u64*)alloc(65536);
  const size_t fixedf = o;
  const size_t availf = (ws_size / 4 > fixedf) ? ws_size / 4 - fixedf : 0;
  int chunkB = (int)(availf / 4194304);  // Mh+Ml per batch = 4M floats worth
  if (chunkB > 8) chunkB = 8;
  if (chunkB < 1) chunkB = 1;
  float* R = ws + o;  // fp32 conv rows, aliases M arena (dead by fc1 time)
  u16* Mh = (u16*)(ws + o);
  u16* Ml = (u16*)(ws + o + (size_t)chunkB * 2097152);

  float* outQ = (float*)d_out;
  float* outD = outQ + 8388608;
  float* outI = outD + 8388608;

  auto run_enc = [&](const float* xin, float* xout, u16* Eh, u16* El,
                     const float* const* pp, int d) {
    k_conv<<<1024, 256, 0, stream>>>(xin, pp[0] + (size_t)d * 256 * 49, pp[1] + d * 256, R);
    k_ln<<<32768, 256, 0, stream>>>(R, pp[2] + d * 256, pp[3] + d * 256, Rh, Rl);
    k_bias2<<<256, 256, 0, stream>>>(pp[8] + (size_t)d * 262144, pp[7] + d * 1024,
                                     pp[9] + d * 256, bias2v);
    hipMemsetAsync(GX2, 0, 8192 * 4, stream);
    for (int b0 = 0; b0 < 8; b0 += chunkB) {
      const int nb = (8 - b0 < chunkB) ? 8 - b0 : chunkB;
      k_gemm<256, 1, 0><<<dim3(8, nb * 32), 256, 0, stream>>>(
          Rh + (size_t)b0 * 4096 * 256, Rl + (size_t)b0 * 4096 * 256,
          W1th_e + (size_t)d * 262144, W1tl_e + (size_t)d * 262144,
          b0 * 4096, 0, Pe[5] + d * 1024, Mh, Ml, nullptr, nullptr, GX2, nullptr);
      k_grn_scale<<<nb, 256, 0, stream>>>(GX2, pp[6] + d * 1024, Sv, b0);
      k_w2prep<<<nb * 256, 256, 0, stream>>>(pp[8] + (size_t)d * 262144, Sv, b0, W2sh, W2sl);
      k_gemm<1024, 1, 1><<<dim3(2, nb * 32), 256, 0, stream>>>(
          Mh, Ml, W2sh, W2sl, b0 * 4096, 262144LL, bias2v,
          Eh ? Eh + (size_t)b0 * 4096 * 256 : (u16*)nullptr,
          El ? El + (size_t)b0 * 4096 * 256 : (u16*)nullptr,
          xout, xin, nullptr, nullptr);
    }
  };

  auto run_dec = [&](const float* xin, float* xout, const float* const* pp, int d) {
    k_conv<<<1024, 256, 0, stream>>>(xin, pp[0] + (size_t)d * 256 * 49, pp[1] + d * 256, R);
    k_ln<<<32768, 256, 0, stream>>>(R, pp[2] + d * 256, pp[3] + d * 256, Rh, Rl);
    k_bias2<<<256, 256, 0, stream>>>(pp[8] + (size_t)d * 262144, pp[7] + d * 1024,
                                     pp[9] + d * 256, bias2v);
    hipMemsetAsync(GX2, 0, 8192 * 4, stream);
    for (int b0 = 0; b0 < 8; b0 += chunkB) {
      const int nb = (8 - b0 < chunkB) ? 8 - b0 : chunkB;
      k_gemm<256, 0, 0><<<dim3(8, nb * 32), 256, 0, stream>>>(
          Rh + (size_t)b0 * 4096 * 256, nullptr,
          W1th_d + (size_t)d * 262144, nullptr,
          b0 * 4096, 0, Pd[5] + d * 1024, Mh, nullptr, nullptr, nullptr, GX2, nullptr);
      k_grn_scale<<<nb, 256, 0, stream>>>(GX2, pp[6] + d * 1024, Sv, b0);
      k_w2prep<<<nb * 256, 256, 0, stream>>>(pp[8] + (size_t)d * 262144, Sv, b0, W2sh, W2sl);
      k_gemm<1024, 0, 1><<<dim3(2, nb * 32), 256, 0, stream>>>(
          Mh, nullptr, W2sh, nullptr, b0 * 4096, 262144LL, bias2v,
          nullptr, nullptr, xout, xin, nullptr, nullptr);
    }
  };

  // prep
  k_wt<<<2048, 256, 0, stream>>>(Pe[4], W1th_e, W1tl_e);
  k_wt<<<2048, 256, 0, stream>>>(Pd[4], W1th_d, W1tl_d);
  k_csplit<<<1024, 256, 0, stream>>>(cbk, Ch, Cl);
  k_c2<<<4, 256, 0, stream>>>(cbk, C2v);

  // encoder (split-bf16, fused 3-term)
  run_enc(x, P1, nullptr, nullptr, Pe, 0);
  run_enc(P1, nullptr, Rh, Rl, Pe, 1);  // E -> Rh/Rl, no NCHW out

  // VQ
  k_rownorm<<<512, 256, 0, stream>>>(Rh, Rl, tn);
  hipMemsetAsync(pk, 0xFF, 32768 * 8, stream);
  k_gemm<256, 1, 2><<<dim3(8, 256), 256, 0, stream>>>(Rh, Rl, Ch, Cl, 0, 0,
                                                      C2v, nullptr, nullptr, nullptr,
                                                      tn, nullptr, pk);
  k_idx<<<128, 256, 0, stream>>>(pk, outI);
  k_gather<<<2048, 256, 0, stream>>>(pk, cbk, outQ);

  // decoder (plain bf16)
  run_dec(outQ, P1, Pd, 0);
  run_dec(P1, outD, Pd, 1);
}

// Round 4
// 1295.132 us; speedup vs baseline: 3.3825x; 1.1936x over previous
//
#include <hip/hip_runtime.h>
#include <math.h>
#include <stdint.h>

typedef unsigned short u16;
typedef unsigned long long u64;
typedef __attribute__((ext_vector_type(8))) short bf16x8;
typedef __attribute__((ext_vector_type(4))) float f32x4;

__device__ __forceinline__ u16 bfhi(float v) {
  unsigned u = __float_as_uint(v);
  u += 0x7FFFu + ((u >> 16) & 1u);
  return (u16)(u >> 16);
}
__device__ __forceinline__ float b2f(u16 h) { return __uint_as_float((unsigned)h << 16); }

__device__ __forceinline__ void gload16(void* lds, const void* g) {
  __builtin_amdgcn_global_load_lds(
      (const __attribute__((address_space(1))) unsigned int*)g,
      (__attribute__((address_space(3))) unsigned int*)lds, 16, 0, 0);
}

// ---------- depthwise conv 7x7 + bias: one channel plane per block ----------
// LDS: 70 rows x pitch 76, center at col' = w + 4 + 4*((row>>2)&1)  (bank-ideal reads)
__global__ __launch_bounds__(256) void k_conv(const float* __restrict__ in,
                                              const float* __restrict__ cw,
                                              const float* __restrict__ cb,
                                              float* __restrict__ rows) {
  const int bx = blockIdx.x;  // 8b x 256c
  const int b = bx >> 8, c = bx & 255;
  __shared__ float patch[70 * 76];
  const int t = threadIdx.x;
  const float* plane = in + (size_t)bx * 4096;
  // stage 1330 float4 chunks (19 per row)
  for (int i = t; i < 1330; i += 256) {
    const int row = i / 19, cf = i - row * 19;
    const int bit = (row >> 2) & 1;
    const int gf = cf - 1 - bit;  // global float4 index
    const int h = row - 3;
    float4 v = {0.f, 0.f, 0.f, 0.f};
    if ((unsigned)h < 64u && (unsigned)gf < 16u) v = *(const float4*)(plane + h * 64 + gf * 4);
    *(float4*)(patch + row * 76 + cf * 4) = v;
  }
  const float* wp = cw + c * 49;  // block-uniform -> SGPR loads
  float wt[49];
#pragma unroll
  for (int i = 0; i < 49; ++i) wt[i] = wp[i];
  const float bias = cb[c];
  __syncthreads();
  const int j = t & 7, i = t >> 3;  // w0 = 8j, output rows 2i, 2i+1
  const int w0 = j * 8, h0 = i * 2;
  float acc[2][8];
#pragma unroll
  for (int dr = 0; dr < 2; ++dr)
#pragma unroll
    for (int ww = 0; ww < 8; ++ww) acc[dr][ww] = bias;
#pragma unroll
  for (int r = 0; r < 8; ++r) {  // patch rows h0 .. h0+7 (global h0-3 .. h0+4)
    const int prow = h0 + r;
    const int bit = (prow >> 2) & 1;
    const float* base = patch + prow * 76 + w0 + 4 * bit;
    float win[16];
#pragma unroll
    for (int q = 0; q < 4; ++q) {
      const float4 v = *(const float4*)(base + q * 4);
      win[q * 4 + 0] = v.x; win[q * 4 + 1] = v.y;
      win[q * 4 + 2] = v.z; win[q * 4 + 3] = v.w;
    }
#pragma unroll
    for (int dr = 0; dr < 2; ++dr) {
      const int kh = r - dr;
      if (kh >= 0 && kh < 7) {
#pragma unroll
        for (int kw = 0; kw < 7; ++kw) {
          const float wv = wt[kh * 7 + kw];
#pragma unroll
          for (int ww = 0; ww < 8; ++ww)
            acc[dr][ww] = fmaf(win[ww + kw + 1], wv, acc[dr][ww]);
        }
      }
    }
  }
#pragma unroll
  for (int dr = 0; dr < 2; ++dr) {
    const int hh = h0 + dr;
#pragma unroll
    for (int ww = 0; ww < 8; ++ww) {
      const int n = (b * 64 + hh) * 64 + w0 + ww;
      rows[(size_t)n * 256 + c] = acc[dr][ww];
    }
  }
}

// ---------- LayerNorm over channels, wave-per-pixel -> bf16 hi/lo rows ----------
__global__ __launch_bounds__(256) void k_ln(const float* __restrict__ rows,
                                            const float* __restrict__ g,
                                            const float* __restrict__ bt,
                                            u16* __restrict__ Rh, u16* __restrict__ Rl) {
  const int t = threadIdx.x;
  const int wv = t >> 6, l = t & 63;
  const float4 gv = *(const float4*)(g + l * 4);
  const float4 bv = *(const float4*)(bt + l * 4);
#pragma unroll 1
  for (int it = 0; it < 4; ++it) {
    const int n = blockIdx.x * 16 + it * 4 + wv;
    const float4 v = *(const float4*)(rows + (size_t)n * 256 + l * 4);
    float s = (v.x + v.y) + (v.z + v.w);
#pragma unroll
    for (int o = 32; o > 0; o >>= 1) s += __shfl_xor(s, o);
    const float mu = s * (1.0f / 256.0f);
    float4 d;
    d.x = v.x - mu; d.y = v.y - mu; d.z = v.z - mu; d.w = v.w - mu;
    float s2 = (d.x * d.x + d.y * d.y) + (d.z * d.z + d.w * d.w);
#pragma unroll
    for (int o = 32; o > 0; o >>= 1) s2 += __shfl_xor(s2, o);
    const float rs = 1.0f / sqrtf(s2 * (1.0f / 256.0f) + 1e-5f);
    float y[4] = {d.x * rs * gv.x + bv.x, d.y * rs * gv.y + bv.y,
                  d.z * rs * gv.z + bv.z, d.w * rs * gv.w + bv.w};
    ushort4 hh, ll;
    hh.x = bfhi(y[0]); ll.x = bfhi(y[0] - b2f(hh.x));
    hh.y = bfhi(y[1]); ll.y = bfhi(y[1] - b2f(hh.y));
    hh.z = bfhi(y[2]); ll.z = bfhi(y[2] - b2f(hh.z));
    hh.w = bfhi(y[3]); ll.w = bfhi(y[3] - b2f(hh.w));
    *(ushort4*)(Rh + (size_t)n * 256 + l * 4) = hh;
    *(ushort4*)(Rl + (size_t)n * 256 + l * 4) = ll;
  }
}

// ---------- fused-term MFMA GEMM: C = (Ah+Al) * (Bh+Bl)^T (drop lo*lo) ----------
// EPI 0: fc1 (+bias, GELU, split->Mh/Ml, GRN sumsq atomics)
// EPI 1: fc2 (+bias, +xin NCHW residual via LDS transpose; xout NCHW and/or Eh/El rows)
// EPI 2: vq  (d2 = (tn - 2a) + c2, packed u64 atomicMin per row)
template <int KD, int SPLIT, int EPI>
__global__ __launch_bounds__(256) void k_gemm(
    const u16* __restrict__ Ah_, const u16* __restrict__ Al_,
    const u16* __restrict__ Bh_, const u16* __restrict__ Bl_,
    const int row0, const long long bstride,
    const float* __restrict__ pbias,
    u16* __restrict__ poh, u16* __restrict__ pol,
    float* __restrict__ pxout, const float* __restrict__ pxin,
    float* __restrict__ pgx2, u64* __restrict__ pmin) {
  constexpr int STAGE_B = (SPLIT ? 4 : 2) * 16384;
  constexpr int TRANS_B = (EPI == 1) ? 64 * 129 * 4 : 0;
  constexpr int SMEM_B = STAGE_B > TRANS_B ? STAGE_B : TRANS_B;
  __shared__ __align__(16) char smem[SMEM_B];
  u16* As_h = (u16*)smem;
  u16* As_l = (u16*)(smem + 16384);
  u16* Bs_h = (u16*)(smem + (SPLIT ? 32768 : 16384));
  u16* Bs_l = (u16*)(smem + 49152);

  const int t = threadIdx.x;
  const int w = t >> 6, l = t & 63;
  const int quad = l >> 4, lm = l & 15;
  const int wr = (w & 1) * 64, wc = (w >> 1) * 64;
  const int colt = blockIdx.x, rowt = blockIdx.y;
  const int nblk0 = rowt * 128;
  const int bglob = (row0 + nblk0) >> 12;

  const u16* Agh = Ah_ + (size_t)nblk0 * KD;
  const u16* Agl = SPLIT ? (Al_ + (size_t)nblk0 * KD) : Ah_;
  const u16* Bgh = Bh_ + (size_t)bglob * (size_t)bstride + (size_t)(colt * 128) * KD;
  const u16* Bgl = SPLIT ? (Bl_ + (size_t)bglob * (size_t)bstride + (size_t)(colt * 128) * KD) : Bh_;

  f32x4 acc[4][4];
  const f32x4 zz = {0.f, 0.f, 0.f, 0.f};
#pragma unroll
  for (int i = 0; i < 4; ++i)
#pragma unroll
    for (int j = 0; j < 4; ++j) acc[i][j] = zz;

  auto stage = [&](u16* Sp, const u16* Gp, int ks) {
#pragma unroll
    for (int ii = 0; ii < 4; ++ii) {
      const int o = ii * 4096 + t * 16;  // byte offset in 16KB slab
      const int row = o >> 7;
      const int kl = (((o >> 4) & 7) ^ (row & 7)) << 3;  // swizzled source chunk
      gload16((char*)Sp + o, Gp + (size_t)row * KD + ks * 64 + kl);
    }
  };

#pragma unroll 1
  for (int ks = 0; ks < KD / 64; ++ks) {
    stage(As_h, Agh, ks);
    stage(Bs_h, Bgh, ks);
    if constexpr (SPLIT) {
      stage(As_l, Agl, ks);
      stage(Bs_l, Bgl, ks);
    }
    __syncthreads();
#pragma unroll
    for (int kk = 0; kk < 2; ++kk) {
      bf16x8 ah[4], bh[4];
#pragma unroll
      for (int i = 0; i < 4; ++i) {
        const int row = wr + i * 16 + lm;
        ah[i] = *(const bf16x8*)(As_h + row * 64 + (((kk * 4 + quad) ^ (row & 7)) << 3));
        const int col = wc + i * 16 + lm;
        bh[i] = *(const bf16x8*)(Bs_h + col * 64 + (((kk * 4 + quad) ^ (col & 7)) << 3));
      }
#pragma unroll
      for (int i = 0; i < 4; ++i)
#pragma unroll
        for (int j = 0; j < 4; ++j)
          acc[i][j] = __builtin_amdgcn_mfma_f32_16x16x32_bf16(ah[i], bh[j], acc[i][j], 0, 0, 0);
      if constexpr (SPLIT) {
        bf16x8 xl[4];
#pragma unroll
        for (int i = 0; i < 4; ++i) {
          const int row = wr + i * 16 + lm;
          xl[i] = *(const bf16x8*)(As_l + row * 64 + (((kk * 4 + quad) ^ (row & 7)) << 3));
        }
#pragma unroll
        for (int i = 0; i < 4; ++i)
#pragma unroll
          for (int j = 0; j < 4; ++j)
            acc[i][j] = __builtin_amdgcn_mfma_f32_16x16x32_bf16(xl[i], bh[j], acc[i][j], 0, 0, 0);
#pragma unroll
        for (int i = 0; i < 4; ++i) {
          const int col = wc + i * 16 + lm;
          xl[i] = *(const bf16x8*)(Bs_l + col * 64 + (((kk * 4 + quad) ^ (col & 7)) << 3));
        }
#pragma unroll
        for (int i = 0; i < 4; ++i)
#pragma unroll
          for (int j = 0; j < 4; ++j)
            acc[i][j] = __builtin_amdgcn_mfma_f32_16x16x32_bf16(ah[i], xl[j], acc[i][j], 0, 0, 0);
      }
    }
    __syncthreads();
  }

  if constexpr (EPI == 0) {
    float csum[4] = {0.f, 0.f, 0.f, 0.f};
    float bv[4];
#pragma unroll
    for (int j = 0; j < 4; ++j) bv[j] = pbias[colt * 128 + wc + j * 16 + lm];
#pragma unroll
    for (int i = 0; i < 4; ++i) {
#pragma unroll
      for (int r = 0; r < 4; ++r) {
        const int row = nblk0 + wr + i * 16 + quad * 4 + r;
#pragma unroll
        for (int j = 0; j < 4; ++j) {
          const int col = colt * 128 + wc + j * 16 + lm;
          const float x = acc[i][j][r] + bv[j];
          const float gl = 0.5f * x * (1.0f + erff(x * 0.70710678118654752f));
          csum[j] = fmaf(gl, gl, csum[j]);
          const size_t idx = (size_t)row * 1024 + col;
          const u16 h = bfhi(gl);
          poh[idx] = h;
          if constexpr (SPLIT) pol[idx] = bfhi(gl - b2f(h));
        }
      }
    }
#pragma unroll
    for (int j = 0; j < 4; ++j) {
      float cs = csum[j];
      cs += __shfl_xor(cs, 16);
      cs += __shfl_xor(cs, 32);
      if (quad == 0)
        unsafeAtomicAdd(&pgx2[bglob * 1024 + colt * 128 + wc + j * 16 + lm], cs);
    }
  } else if constexpr (EPI == 1) {
    float* T = (float*)smem;  // [64 cols][pitch 129] f32, per col-half
    const int pg0 = (row0 + nblk0) & 4095;
    const int bb = (row0 + nblk0) >> 12;
#pragma unroll 1
    for (int h = 0; h < 2; ++h) {
      __syncthreads();
      if ((w >> 1) == h) {
#pragma unroll
        for (int i = 0; i < 4; ++i) {
          const int row = wr + i * 16 + quad * 4;
#pragma unroll
          for (int j = 0; j < 4; ++j) {
            const int cl = j * 16 + lm;
#pragma unroll
            for (int r = 0; r < 4; ++r) T[cl * 129 + row + r] = acc[i][j][r];
          }
        }
      }
      __syncthreads();
      const int lp = (l & 31) * 4;
      const int ch2 = l >> 5;
#pragma unroll
      for (int step = 0; step < 8; ++step) {
        const int cl = w * 16 + step * 2 + ch2;
        const int cg = colt * 128 + h * 64 + cl;
        float4 tv = *(float4*)&T[cl * 129 + lp];
        const float bv2 = pbias[cg];
        const size_t nchw = (((size_t)(bb * 256 + cg)) << 12) + pg0 + lp;
        const float4 xv = *(const float4*)(pxin + nchw);
        float4 z;
        z.x = tv.x + bv2 + xv.x;
        z.y = tv.y + bv2 + xv.y;
        z.z = tv.z + bv2 + xv.z;
        z.w = tv.w + bv2 + xv.w;
        if (pxout) *(float4*)(pxout + nchw) = z;
        if (poh) *(float4*)&T[cl * 129 + lp] = z;
      }
      if (poh) {
        __syncthreads();
        const int cl3 = t & 63;
        const int cg3 = colt * 128 + h * 64 + cl3;
        const int r0 = (t >> 6) * 32;
#pragma unroll
        for (int n = 0; n < 32; ++n) {
          const float z = T[cl3 * 129 + r0 + n];
          const size_t idx = (size_t)(nblk0 + r0 + n) * 256 + cg3;
          const u16 hh = bfhi(z);
          poh[idx] = hh;
          pol[idx] = bfhi(z - b2f(hh));
        }
      }
    }
  } else {
#pragma unroll
    for (int i = 0; i < 4; ++i) {
#pragma unroll
      for (int r = 0; r < 4; ++r) {
        const int nloc = nblk0 + wr + i * 16 + quad * 4 + r;
        const float tnv = pxin[nloc];
        u64 best = ~0ULL;
#pragma unroll
        for (int j = 0; j < 4; ++j) {
          const int code = colt * 128 + wc + j * 16 + lm;
          const float d = __fadd_rn(__fsub_rn(tnv, __fmul_rn(2.0f, acc[i][j][r])), pbias[code]);
          const u64 pk = (((u64)__float_as_uint(d)) << 32) | (unsigned)code;
          best = pk < best ? pk : best;
        }
#pragma unroll
        for (int off = 1; off < 16; off <<= 1) {
          unsigned lo32 = (unsigned)best, hi32 = (unsigned)(best >> 32);
          lo32 = __shfl_xor(lo32, off);
          hi32 = __shfl_xor(hi32, off);
          const u64 o2 = (((u64)hi32) << 32) | lo32;
          best = o2 < best ? o2 : best;
        }
        if (lm == 0) atomicMin(pmin + nloc, best);
      }
    }
  }
}

// ---------- row sumsq (tn) from bf16 hi/lo E rows ----------
__global__ __launch_bounds__(256) void k_rownorm(const u16* __restrict__ Eh,
                                                 const u16* __restrict__ El,
                                                 float* __restrict__ tn) {
  const int t = threadIdx.x;
  const int r = t >> 2, p = t & 3;
  const int n = blockIdx.x * 64 + r;
  const u16* ph = Eh + (size_t)n * 256 + p * 64;
  const u16* pl = El + (size_t)n * 256 + p * 64;
  float s = 0.f;
#pragma unroll
  for (int j = 0; j < 8; ++j) {
    const uint4 hv = *(const uint4*)(ph + j * 8);
    const uint4 lv = *(const uint4*)(pl + j * 8);
    const unsigned hu[4] = {hv.x, hv.y, hv.z, hv.w};
    const unsigned lu[4] = {lv.x, lv.y, lv.z, lv.w};
#pragma unroll
    for (int q = 0; q < 4; ++q) {
      const float v0 = b2f((u16)(hu[q] & 0xffff)) + b2f((u16)(lu[q] & 0xffff));
      const float v1 = b2f((u16)(hu[q] >> 16)) + b2f((u16)(lu[q] >> 16));
      s = fmaf(v0, v0, s);
      s = fmaf(v1, v1, s);
    }
  }
  s += __shfl_xor(s, 1);
  s += __shfl_xor(s, 2);
  if (p == 0) tn[n] = s;
}

// ---------- GRN scale s = 1 + gg*nx from sumsq ----------
__global__ __launch_bounds__(256) void k_grn_scale(const float* __restrict__ GX2,
                                                   const float* __restrict__ gg,
                                                   float* __restrict__ S, int b0) {
  const int b = b0 + blockIdx.x, t = threadIdx.x;
  const float* gxb = GX2 + (size_t)b * 1024;
  float gx[4];
  float s = 0.f;
#pragma unroll
  for (int i = 0; i < 4; ++i) {
    gx[i] = sqrtf(gxb[t + i * 256]);
    s += gx[i];
  }
  const int w = t >> 6, l = t & 63;
#pragma unroll
  for (int o = 32; o > 0; o >>= 1) s += __shfl_down(s, o);
  __shared__ float red[4];
  __shared__ float bc;
  if (l == 0) red[w] = s;
  __syncthreads();
  if (t == 0) bc = 1.0f / ((red[0] + red[1] + red[2] + red[3]) * (1.0f / 1024.0f) + 1e-6f);
  __syncthreads();
  const float inv = bc;
#pragma unroll
  for (int i = 0; i < 4; ++i)
    S[(size_t)b * 1024 + t + i * 256] = fmaf(gg[t + i * 256], gx[i] * inv, 1.0f);
}

// ---------- per-batch scaled+split+transposed W2 ----------
__global__ __launch_bounds__(256) void k_w2prep(const float* __restrict__ W2,
                                                const float* __restrict__ S, int b0,
                                                u16* __restrict__ Wh, u16* __restrict__ Wl) {
  const int bx = blockIdx.x;
  const int b = b0 + (bx >> 8), n = bx & 255;
  const int t = threadIdx.x;
#pragma unroll
  for (int j = 0; j < 4; ++j) {
    const int k = t + j * 256;
    const float v = W2[(size_t)k * 256 + n] * S[(size_t)b * 1024 + k];
    const size_t idx = ((size_t)(b * 256 + n)) * 1024 + k;
    const u16 h = bfhi(v);
    Wh[idx] = h;
    Wl[idx] = bfhi(v - b2f(h));
  }
}

// ---------- bias2v = b2 + gb @ W2 (one block per output channel) ----------
__global__ __launch_bounds__(256) void k_bias2(const float* __restrict__ W2,
                                               const float* __restrict__ gb,
                                               const float* __restrict__ b2,
                                               float* __restrict__ out) {
  const int c = blockIdx.x, t = threadIdx.x;
  float acc = 0.f;
#pragma unroll
  for (int j = 0; j < 4; ++j) {
    const int k = t + j * 256;
    acc = fmaf(gb[k], W2[(size_t)k * 256 + c], acc);
  }
  const int w = t >> 6, l = t & 63;
#pragma unroll
  for (int o = 32; o > 0; o >>= 1) acc += __shfl_down(acc, o);
  __shared__ float red[4];
  if (l == 0) red[w] = acc;
  __syncthreads();
  if (t == 0) out[c] = red[0] + red[1] + red[2] + red[3] + b2[c];
}

// ---------- W1^T split ----------
__global__ __launch_bounds__(256) void k_wt(const float* __restrict__ W1,
                                            u16* __restrict__ Wh, u16* __restrict__ Wl) {
  const int bx = blockIdx.x;  // d*1024 + n
  const int d = bx >> 10, n = bx & 1023;
  const int k = threadIdx.x;
  const float v = W1[(size_t)d * 262144 + (size_t)k * 1024 + n];
  const size_t idx = (size_t)bx * 256 + k;
  const u16 h = bfhi(v);
  Wh[idx] = h;
  Wl[idx] = bfhi(v - b2f(h));
}

// ---------- codebook split ----------
__global__ __launch_bounds__(256) void k_csplit(const float* __restrict__ C,
                                                u16* __restrict__ Ch, u16* __restrict__ Cl) {
  const size_t i = (size_t)blockIdx.x * 256 + threadIdx.x;
  const float v = C[i];
  const u16 h = bfhi(v);
  Ch[i] = h;
  Cl[i] = bfhi(v - b2f(h));
}

// ---------- numpy-pairwise |c|^2 per code ----------
__device__ __forceinline__ float np_pairwise_sq_256(const float* p) {
  float half[2];
#pragma unroll
  for (int hh = 0; hh < 2; ++hh) {
    float r[8];
#pragma unroll
    for (int j = 0; j < 8; ++j) {
      const float v = p[hh * 128 + j];
      r[j] = __fmul_rn(v, v);
    }
    for (int i = 8; i < 128; i += 8) {
#pragma unroll
      for (int j = 0; j < 8; ++j) {
        const float v = p[hh * 128 + i + j];
        r[j] = __fadd_rn(r[j], __fmul_rn(v, v));
      }
    }
    half[hh] = __fadd_rn(__fadd_rn(__fadd_rn(r[0], r[1]), __fadd_rn(r[2], r[3])),
                         __fadd_rn(__fadd_rn(r[4], r[5]), __fadd_rn(r[6], r[7])));
  }
  return __fadd_rn(half[0], half[1]);
}

__global__ __launch_bounds__(256) void k_c2(const float* __restrict__ cbk, float* __restrict__ c2) {
  const int k = blockIdx.x * 256 + threadIdx.x;
  c2[k] = np_pairwise_sq_256(cbk + (size_t)k * 256);
}

// ---------- index output + quantized gather ----------
__global__ __launch_bounds__(256) void k_idx(const u64* __restrict__ pk, float* __restrict__ outI) {
  const int n = blockIdx.x * 256 + threadIdx.x;
  outI[n] = (float)(unsigned)(pk[n] & 0xffffffffULL);
}

// 64 consecutive pixels per block; lanes = pixels so NCHW writes coalesce
__global__ __launch_bounds__(256) void k_gather(const u64* __restrict__ pk,
                                                const float* __restrict__ cbk,
                                                float* __restrict__ outq) {
  const int t = threadIdx.x;
  const int p0 = blockIdx.x * 64;
  const int b = p0 >> 12, pl = (p0 & 4095) + (t & 63);
  const int cg = t >> 6;  // 4 channel groups of 64
  const int n = p0 + (t & 63);
  const int k = (int)(unsigned)(pk[n] & 0xffffffffULL);
  const float* crow = cbk + (size_t)k * 256 + cg * 64;
  float* ob = outq + (((size_t)(b * 256 + cg * 64)) << 12) + pl;
#pragma unroll 1
  for (int j = 0; j < 16; ++j) {
    const float4 cv = *(const float4*)(crow + j * 4);
    ob[((size_t)(j * 4 + 0)) << 12] = cv.x;
    ob[((size_t)(j * 4 + 1)) << 12] = cv.y;
    ob[((size_t)(j * 4 + 2)) << 12] = cv.z;
    ob[((size_t)(j * 4 + 3)) << 12] = cv.w;
  }
}

extern "C" void kernel_launch(void* const* d_in, const int* in_sizes, int n_in,
                              void* d_out, int out_size, void* d_ws, size_t ws_size,
                              hipStream_t stream) {
  const float* x = (const float*)d_in[0];
  const float* cbk = (const float*)d_in[1];
  const float* Pe[10];
  const float* Pd[10];
  for (int i = 0; i < 10; ++i) Pe[i] = (const float*)d_in[2 + i];
  for (int i = 0; i < 10; ++i) Pd[i] = (const float*)d_in[12 + i];
  // order per dict: conv_w, conv_b, ln_g, ln_b, fc1_w, fc1_b, grn_g, grn_b, fc2_w, fc2_b

  float* ws = (float*)d_ws;
  size_t o = 0;
  auto alloc = [&](size_t nf) {
    float* p = ws + o;
    o += (nf + 63) & ~(size_t)63;
    return p;
  };
  float* P1 = alloc(8388608);      // NCHW ping
  u16* Rh = (u16*)alloc(4194304);  // rows hi (also E hi)
  u16* Rl = (u16*)alloc(4194304);  // rows lo (also E lo)
  u16* W1th_e = (u16*)alloc(262144);
  u16* W1tl_e = (u16*)alloc(262144);
  u16* W1th_d = (u16*)alloc(262144);
  u16* W1tl_d = (u16*)alloc(262144);
  u16* W2sh = (u16*)alloc(1048576);
  u16* W2sl = (u16*)alloc(1048576);
  u16* Ch = (u16*)alloc(131072);
  u16* Cl = (u16*)alloc(131072);
  float* C2v = alloc(1024);
  float* GX2 = alloc(8192);
  float* Sv = alloc(8192);
  float* bias2v = alloc(256);
  float* tn = alloc(32768);
  u64* pk = (u64*)alloc(65536);
  const size_t fixedf = o;
  const size_t availf = (ws_size / 4 > fixedf) ? ws_size / 4 - fixedf : 0;
  int chunkB = (int)(availf / 4194304);  // Mh+Ml per batch = 4M floats worth
  if (chunkB > 8) chunkB = 8;
  if (chunkB < 1) chunkB = 1;
  float* R = ws + o;  // fp32 conv rows, aliases M arena (dead by fc1 time)
  u16* Mh = (u16*)(ws + o);
  u16* Ml = (u16*)(ws + o + (size_t)chunkB * 2097152);

  float* outQ = (float*)d_out;
  float* outD = outQ + 8388608;
  float* outI = outD + 8388608;

  auto run_enc = [&](const float* xin, float* xout, u16* Eh, u16* El,
                     const float* const* pp, int d) {
    k_conv<<<2048, 256, 0, stream>>>(xin, pp[0] + (size_t)d * 256 * 49, pp[1] + d * 256, R);
    k_ln<<<2048, 256, 0, stream>>>(R, pp[2] + d * 256, pp[3] + d * 256, Rh, Rl);
    k_bias2<<<256, 256, 0, stream>>>(pp[8] + (size_t)d * 262144, pp[7] + d * 1024,
                                     pp[9] + d * 256, bias2v);
    hipMemsetAsync(GX2, 0, 8192 * 4, stream);
    for (int b0 = 0; b0 < 8; b0 += chunkB) {
      const int nb = (8 - b0 < chunkB) ? 8 - b0 : chunkB;
      k_gemm<256, 1, 0><<<dim3(8, nb * 32), 256, 0, stream>>>(
          Rh + (size_t)b0 * 4096 * 256, Rl + (size_t)b0 * 4096 * 256,
          W1th_e + (size_t)d * 262144, W1tl_e + (size_t)d * 262144,
          b0 * 4096, 0, Pe[5] + d * 1024, Mh, Ml, nullptr, nullptr, GX2, nullptr);
      k_grn_scale<<<nb, 256, 0, stream>>>(GX2, pp[6] + d * 1024, Sv, b0);
      k_w2prep<<<nb * 256, 256, 0, stream>>>(pp[8] + (size_t)d * 262144, Sv, b0, W2sh, W2sl);
      k_gemm<1024, 1, 1><<<dim3(2, nb * 32), 256, 0, stream>>>(
          Mh, Ml, W2sh, W2sl, b0 * 4096, 262144LL, bias2v,
          Eh ? Eh + (size_t)b0 * 4096 * 256 : (u16*)nullptr,
          El ? El + (size_t)b0 * 4096 * 256 : (u16*)nullptr,
          xout, xin, nullptr, nullptr);
    }
  };

  auto run_dec = [&](const float* xin, float* xout, const float* const* pp, int d) {
    k_conv<<<2048, 256, 0, stream>>>(xin, pp[0] + (size_t)d * 256 * 49, pp[1] + d * 256, R);
    k_ln<<<2048, 256, 0, stream>>>(R, pp[2] + d * 256, pp[3] + d * 256, Rh, Rl);
    k_bias2<<<256, 256, 0, stream>>>(pp[8] + (size_t)d * 262144, pp[7] + d * 1024,
                                     pp[9] + d * 256, bias2v);
    hipMemsetAsync(GX2, 0, 8192 * 4, stream);
    for (int b0 = 0; b0 < 8; b0 += chunkB) {
      const int nb = (8 - b0 < chunkB) ? 8 - b0 : chunkB;
      k_gemm<256, 0, 0><<<dim3(8, nb * 32), 256, 0, stream>>>(
          Rh + (size_t)b0 * 4096 * 256, nullptr,
          W1th_d + (size_t)d * 262144, nullptr,
          b0 * 4096, 0, Pd[5] + d * 1024, Mh, nullptr, nullptr, nullptr, GX2, nullptr);
      k_grn_scale<<<nb, 256, 0, stream>>>(GX2, pp[6] + d * 1024, Sv, b0);
      k_w2prep<<<nb * 256, 256, 0, stream>>>(pp[8] + (size_t)d * 262144, Sv, b0, W2sh, W2sl);
      k_gemm<1024, 0, 1><<<dim3(2, nb * 32), 256, 0, stream>>>(
          Mh, nullptr, W2sh, nullptr, b0 * 4096, 262144LL, bias2v,
          nullptr, nullptr, xout, xin, nullptr, nullptr);
    }
  };

  // prep
  k_wt<<<2048, 256, 0, stream>>>(Pe[4], W1th_e, W1tl_e);
  k_wt<<<2048, 256, 0, stream>>>(Pd[4], W1th_d, W1tl_d);
  k_csplit<<<1024, 256, 0, stream>>>(cbk, Ch, Cl);
  k_c2<<<4, 256, 0, stream>>>(cbk, C2v);

  // encoder (split-bf16, fused 3-term)
  run_enc(x, P1, nullptr, nullptr, Pe, 0);
  run_enc(P1, nullptr, Rh, Rl, Pe, 1);  // E -> Rh/Rl, no NCHW out

  // VQ
  k_rownorm<<<512, 256, 0, stream>>>(Rh, Rl, tn);
  hipMemsetAsync(pk, 0xFF, 32768 * 8, stream);
  k_gemm<256, 1, 2><<<dim3(8, 256), 256, 0, stream>>>(Rh, Rl, Ch, Cl, 0, 0,
                                                      C2v, nullptr, nullptr, nullptr,
                                                      tn, nullptr, pk);
  k_idx<<<128, 256, 0, stream>>>(pk, outI);
  k_gather<<<512, 256, 0, stream>>>(pk, cbk, outQ);

  // decoder (plain bf16)
  run_dec(outQ, P1, Pd, 0);
  run_dec(P1, outD, Pd, 1);
}

// Round 5
// 1025.733 us; speedup vs baseline: 4.2709x; 1.2626x over previous
//
#include <hip/hip_runtime.h>
#include <math.h>
#include <stdint.h>

typedef unsigned short u16;
typedef unsigned long long u64;
typedef __attribute__((ext_vector_type(8))) short bf16x8;
typedef __attribute__((ext_vector_type(4))) float f32x4;

__device__ __forceinline__ u16 bfhi(float v) {
  unsigned u = __float_as_uint(v);
  u += 0x7FFFu + ((u >> 16) & 1u);
  return (u16)(u >> 16);
}
__device__ __forceinline__ float b2f(u16 h) { return __uint_as_float((unsigned)h << 16); }

__device__ __forceinline__ void gload16(void* lds, const void* g) {
  __builtin_amdgcn_global_load_lds(
      (const __attribute__((address_space(1))) unsigned int*)g,
      (__attribute__((address_space(3))) unsigned int*)lds, 16, 0, 0);
}

// ---------- depthwise conv 7x7 + bias: NCHW -> NCHW (coalesced float4 stores) ----------
// LDS: 70 rows x pitch 76, center at col' = w + 4 + 4*((row>>2)&1)  (bank-ideal reads)
__global__ __launch_bounds__(256) void k_conv(const float* __restrict__ in,
                                              const float* __restrict__ cw,
                                              const float* __restrict__ cb,
                                              float* __restrict__ out) {
  const int bx = blockIdx.x;  // 8b x 256c
  const int c = bx & 255;
  __shared__ float patch[70 * 76];
  const int t = threadIdx.x;
  const float* plane = in + (size_t)bx * 4096;
  // stage 1330 float4 chunks (19 per row)
  for (int i = t; i < 1330; i += 256) {
    const int row = i / 19, cf = i - row * 19;
    const int bit = (row >> 2) & 1;
    const int gf = cf - 1 - bit;  // global float4 index
    const int h = row - 3;
    float4 v = {0.f, 0.f, 0.f, 0.f};
    if ((unsigned)h < 64u && (unsigned)gf < 16u) v = *(const float4*)(plane + h * 64 + gf * 4);
    *(float4*)(patch + row * 76 + cf * 4) = v;
  }
  const float* wp = cw + c * 49;  // block-uniform -> SGPR loads
  float wt[49];
#pragma unroll
  for (int i = 0; i < 49; ++i) wt[i] = wp[i];
  const float bias = cb[c];
  __syncthreads();
  const int j = t & 7, i = t >> 3;  // w0 = 8j, output rows 2i, 2i+1
  const int w0 = j * 8, h0 = i * 2;
  float acc[2][8];
#pragma unroll
  for (int dr = 0; dr < 2; ++dr)
#pragma unroll
    for (int ww = 0; ww < 8; ++ww) acc[dr][ww] = bias;
#pragma unroll
  for (int r = 0; r < 8; ++r) {  // patch rows h0 .. h0+7 (global h0-3 .. h0+4)
    const int prow = h0 + r;
    const int bit = (prow >> 2) & 1;
    const float* base = patch + prow * 76 + w0 + 4 * bit;
    float win[16];
#pragma unroll
    for (int q = 0; q < 4; ++q) {
      const float4 v = *(const float4*)(base + q * 4);
      win[q * 4 + 0] = v.x; win[q * 4 + 1] = v.y;
      win[q * 4 + 2] = v.z; win[q * 4 + 3] = v.w;
    }
#pragma unroll
    for (int dr = 0; dr < 2; ++dr) {
      const int kh = r - dr;
      if (kh >= 0 && kh < 7) {
#pragma unroll
        for (int kw = 0; kw < 7; ++kw) {
          const float wv = wt[kh * 7 + kw];
#pragma unroll
          for (int ww = 0; ww < 8; ++ww)
            acc[dr][ww] = fmaf(win[ww + kw + 1], wv, acc[dr][ww]);
        }
      }
    }
  }
  float* op = out + (size_t)bx * 4096;
#pragma unroll
  for (int dr = 0; dr < 2; ++dr) {
    const int hh = h0 + dr;
    float4 o1, o2;
    o1.x = acc[dr][0]; o1.y = acc[dr][1]; o1.z = acc[dr][2]; o1.w = acc[dr][3];
    o2.x = acc[dr][4]; o2.y = acc[dr][5]; o2.z = acc[dr][6]; o2.w = acc[dr][7];
    *(float4*)(op + hh * 64 + w0) = o1;
    *(float4*)(op + hh * 64 + w0 + 4) = o2;
  }
}

// ---------- LN over channels from NCHW, via LDS transpose -> NHWC bf16 hi/lo ----------
// 32 px per block; T[c][p] pitch 33
__global__ __launch_bounds__(256) void k_lnT(const float* __restrict__ src,
                                             const float* __restrict__ g,
                                             const float* __restrict__ bt,
                                             u16* __restrict__ Rh, u16* __restrict__ Rl,
                                             const int wlo) {
  __shared__ float T[256 * 33];
  __shared__ float red[8 * 32];
  __shared__ float gs[256], bs[256];
  const int t = threadIdx.x;
  const int n0 = blockIdx.x * 32;
  const int b = n0 >> 12, pl = n0 & 4095;
  gs[t] = g[t];
  bs[t] = bt[t];
  const int m = t & 7, h = t >> 3;  // m: px quad, h: channel-in-group
  const float* sp = src + (((size_t)(b * 256)) << 12) + pl + m * 4;
#pragma unroll
  for (int it = 0; it < 8; ++it) {
    const int c = it * 32 + h;
    const float4 v = *(const float4*)(sp + ((size_t)c << 12));
    *(float4*)(T + c * 33 + m * 4) = v;
  }
  __syncthreads();
  const int p = t & 31, qq = t >> 5;
  float s = 0.f;
#pragma unroll
  for (int jj = 0; jj < 32; ++jj) s += T[(qq * 32 + jj) * 33 + p];
  red[qq * 32 + p] = s;
  __syncthreads();
  float tot = 0.f;
#pragma unroll
  for (int k = 0; k < 8; ++k) tot += red[k * 32 + p];
  const float mu = tot * (1.0f / 256.0f);
  __syncthreads();
  float s2 = 0.f;
#pragma unroll
  for (int jj = 0; jj < 32; ++jj) {
    const float d = T[(qq * 32 + jj) * 33 + p] - mu;
    s2 = fmaf(d, d, s2);
  }
  red[qq * 32 + p] = s2;
  __syncthreads();
  float tot2 = 0.f;
#pragma unroll
  for (int k = 0; k < 8; ++k) tot2 += red[k * 32 + p];
  const float rs = 1.0f / sqrtf(tot2 * (1.0f / 256.0f) + 1e-5f);
#pragma unroll
  for (int jj = 0; jj < 32; ++jj) {
    const int c = qq * 32 + jj;
    const float y = (T[c * 33 + p] - mu) * rs * gs[c] + bs[c];
    const u16 hh = bfhi(y);
    const u16 ll = bfhi(y - b2f(hh));
    ((unsigned*)T)[c * 33 + p] = ((unsigned)hh << 16) | ll;
  }
  __syncthreads();
  const int w = t >> 6, l = t & 63;
  const unsigned* Tu = (const unsigned*)T;
#pragma unroll
  for (int r = 0; r < 4; ++r) {
    const int px = r * 8 + w * 2 + (l >> 5);
    const int c0 = (l & 31) * 8;
    unsigned hp[4], lp[4];
#pragma unroll
    for (int jj = 0; jj < 4; ++jj) {
      const unsigned a = Tu[(c0 + 2 * jj) * 33 + px];
      const unsigned bb = Tu[(c0 + 2 * jj + 1) * 33 + px];
      hp[jj] = (a >> 16) | (bb & 0xffff0000u);
      lp[jj] = (a & 0xffffu) | (bb << 16);
    }
    const size_t base = (size_t)(n0 + px) * 256 + c0;
    *(uint4*)(Rh + base) = make_uint4(hp[0], hp[1], hp[2], hp[3]);
    if (wlo) *(uint4*)(Rl + base) = make_uint4(lp[0], lp[1], lp[2], lp[3]);
  }
}

// ---------- fused-term MFMA GEMM: C = (Ah+Al) * (Bh+Bl)^T (drop lo*lo) ----------
// EPI 0: fc1 (+bias, GELU, split->Mh/Ml, GRN sumsq atomics)
// EPI 1: fc2 (+bias, +xin NCHW residual via LDS transpose; xout NCHW and/or Eh/El rows)
// EPI 2: vq  (d2 = (tn - 2a) + c2, packed u64 atomicMin per row)
template <int KD, int SPLIT, int EPI>
__global__ __launch_bounds__(256) void k_gemm(
    const u16* __restrict__ Ah_, const u16* __restrict__ Al_,
    const u16* __restrict__ Bh_, const u16* __restrict__ Bl_,
    const int row0, const long long bstride,
    const float* __restrict__ pbias,
    u16* __restrict__ poh, u16* __restrict__ pol,
    float* __restrict__ pxout, const float* __restrict__ pxin,
    float* __restrict__ pgx2, u64* __restrict__ pmin) {
  constexpr int STAGE_B = (SPLIT ? 4 : 2) * 16384;
  constexpr int TRANS_B = (EPI == 1) ? 64 * 129 * 4 : 0;
  constexpr int SMEM_B = STAGE_B > TRANS_B ? STAGE_B : TRANS_B;
  __shared__ __align__(16) char smem[SMEM_B];
  u16* As_h = (u16*)smem;
  u16* As_l = (u16*)(smem + 16384);
  u16* Bs_h = (u16*)(smem + (SPLIT ? 32768 : 16384));
  u16* Bs_l = (u16*)(smem + 49152);

  const int t = threadIdx.x;
  const int w = t >> 6, l = t & 63;
  const int quad = l >> 4, lm = l & 15;
  const int wr = (w & 1) * 64, wc = (w >> 1) * 64;
  const int colt = blockIdx.x, rowt = blockIdx.y;
  const int nblk0 = rowt * 128;
  const int bglob = (row0 + nblk0) >> 12;

  const u16* Agh = Ah_ + (size_t)nblk0 * KD;
  const u16* Agl = SPLIT ? (Al_ + (size_t)nblk0 * KD) : Ah_;
  const u16* Bgh = Bh_ + (size_t)bglob * (size_t)bstride + (size_t)(colt * 128) * KD;
  const u16* Bgl = SPLIT ? (Bl_ + (size_t)bglob * (size_t)bstride + (size_t)(colt * 128) * KD) : Bh_;

  f32x4 acc[4][4];
  const f32x4 zz = {0.f, 0.f, 0.f, 0.f};
#pragma unroll
  for (int i = 0; i < 4; ++i)
#pragma unroll
    for (int j = 0; j < 4; ++j) acc[i][j] = zz;

  auto stage = [&](u16* Sp, const u16* Gp, int ks) {
#pragma unroll
    for (int ii = 0; ii < 4; ++ii) {
      const int o = ii * 4096 + t * 16;  // byte offset in 16KB slab
      const int row = o >> 7;
      const int kl = (((o >> 4) & 7) ^ (row & 7)) << 3;  // swizzled source chunk
      gload16((char*)Sp + o, Gp + (size_t)row * KD + ks * 64 + kl);
    }
  };

#pragma unroll 1
  for (int ks = 0; ks < KD / 64; ++ks) {
    stage(As_h, Agh, ks);
    stage(Bs_h, Bgh, ks);
    if constexpr (SPLIT) {
      stage(As_l, Agl, ks);
      stage(Bs_l, Bgl, ks);
    }
    __syncthreads();
#pragma unroll
    for (int kk = 0; kk < 2; ++kk) {
      bf16x8 ah[4], bh[4];
#pragma unroll
      for (int i = 0; i < 4; ++i) {
        const int row = wr + i * 16 + lm;
        ah[i] = *(const bf16x8*)(As_h + row * 64 + (((kk * 4 + quad) ^ (row & 7)) << 3));
        const int col = wc + i * 16 + lm;
        bh[i] = *(const bf16x8*)(Bs_h + col * 64 + (((kk * 4 + quad) ^ (col & 7)) << 3));
      }
#pragma unroll
      for (int i = 0; i < 4; ++i)
#pragma unroll
        for (int j = 0; j < 4; ++j)
          acc[i][j] = __builtin_amdgcn_mfma_f32_16x16x32_bf16(ah[i], bh[j], acc[i][j], 0, 0, 0);
      if constexpr (SPLIT) {
        bf16x8 xl[4];
#pragma unroll
        for (int i = 0; i < 4; ++i) {
          const int row = wr + i * 16 + lm;
          xl[i] = *(const bf16x8*)(As_l + row * 64 + (((kk * 4 + quad) ^ (row & 7)) << 3));
        }
#pragma unroll
        for (int i = 0; i < 4; ++i)
#pragma unroll
          for (int j = 0; j < 4; ++j)
            acc[i][j] = __builtin_amdgcn_mfma_f32_16x16x32_bf16(xl[i], bh[j], acc[i][j], 0, 0, 0);
#pragma unroll
        for (int i = 0; i < 4; ++i) {
          const int col = wc + i * 16 + lm;
          xl[i] = *(const bf16x8*)(Bs_l + col * 64 + (((kk * 4 + quad) ^ (col & 7)) << 3));
        }
#pragma unroll
        for (int i = 0; i < 4; ++i)
#pragma unroll
          for (int j = 0; j < 4; ++j)
            acc[i][j] = __builtin_amdgcn_mfma_f32_16x16x32_bf16(ah[i], xl[j], acc[i][j], 0, 0, 0);
      }
    }
    __syncthreads();
  }

  if constexpr (EPI == 0) {
    float csum[4] = {0.f, 0.f, 0.f, 0.f};
    float bv[4];
#pragma unroll
    for (int j = 0; j < 4; ++j) bv[j] = pbias[colt * 128 + wc + j * 16 + lm];
#pragma unroll
    for (int i = 0; i < 4; ++i) {
#pragma unroll
      for (int r = 0; r < 4; ++r) {
        const int row = nblk0 + wr + i * 16 + quad * 4 + r;
#pragma unroll
        for (int j = 0; j < 4; ++j) {
          const int col = colt * 128 + wc + j * 16 + lm;
          const float x = acc[i][j][r] + bv[j];
          const float gl = 0.5f * x * (1.0f + erff(x * 0.70710678118654752f));
          csum[j] = fmaf(gl, gl, csum[j]);
          const size_t idx = (size_t)row * 1024 + col;
          const u16 h = bfhi(gl);
          poh[idx] = h;
          if constexpr (SPLIT) pol[idx] = bfhi(gl - b2f(h));
        }
      }
    }
#pragma unroll
    for (int j = 0; j < 4; ++j) {
      float cs = csum[j];
      cs += __shfl_xor(cs, 16);
      cs += __shfl_xor(cs, 32);
      if (quad == 0)
        unsafeAtomicAdd(&pgx2[bglob * 1024 + colt * 128 + wc + j * 16 + lm], cs);
    }
  } else if constexpr (EPI == 1) {
    float* T = (float*)smem;  // [64 cols][pitch 129] f32, per col-half
    const int pg0 = (row0 + nblk0) & 4095;
    const int bb = (row0 + nblk0) >> 12;
#pragma unroll 1
    for (int h = 0; h < 2; ++h) {
      __syncthreads();
      if ((w >> 1) == h) {
#pragma unroll
        for (int i = 0; i < 4; ++i) {
          const int row = wr + i * 16 + quad * 4;
#pragma unroll
          for (int j = 0; j < 4; ++j) {
            const int cl = j * 16 + lm;
#pragma unroll
            for (int r = 0; r < 4; ++r) T[cl * 129 + row + r] = acc[i][j][r];
          }
        }
      }
      __syncthreads();
      const int lp = (l & 31) * 4;
      const int ch2 = l >> 5;
#pragma unroll
      for (int step = 0; step < 8; ++step) {
        const int cl = w * 16 + step * 2 + ch2;
        const int cg = colt * 128 + h * 64 + cl;
        float4 tv = *(float4*)&T[cl * 129 + lp];
        const float bv2 = pbias[cg];
        const size_t nchw = (((size_t)(bb * 256 + cg)) << 12) + pg0 + lp;
        const float4 xv = *(const float4*)(pxin + nchw);
        float4 z;
        z.x = tv.x + bv2 + xv.x;
        z.y = tv.y + bv2 + xv.y;
        z.z = tv.z + bv2 + xv.z;
        z.w = tv.w + bv2 + xv.w;
        if (pxout) *(float4*)(pxout + nchw) = z;
        if (poh) *(float4*)&T[cl * 129 + lp] = z;
      }
      if (poh) {
        __syncthreads();
        const int cl3 = t & 63;
        const int cg3 = colt * 128 + h * 64 + cl3;
        const int r0 = (t >> 6) * 32;
#pragma unroll
        for (int n = 0; n < 32; ++n) {
          const float z = T[cl3 * 129 + r0 + n];
          const size_t idx = (size_t)(nblk0 + r0 + n) * 256 + cg3;
          const u16 hh = bfhi(z);
          poh[idx] = hh;
          pol[idx] = bfhi(z - b2f(hh));
        }
      }
    }
  } else {
#pragma unroll
    for (int i = 0; i < 4; ++i) {
#pragma unroll
      for (int r = 0; r < 4; ++r) {
        const int nloc = nblk0 + wr + i * 16 + quad * 4 + r;
        const float tnv = pxin[nloc];
        u64 best = ~0ULL;
#pragma unroll
        for (int j = 0; j < 4; ++j) {
          const int code = colt * 128 + wc + j * 16 + lm;
          const float d = __fadd_rn(__fsub_rn(tnv, __fmul_rn(2.0f, acc[i][j][r])), pbias[code]);
          const u64 pk = (((u64)__float_as_uint(d)) << 32) | (unsigned)code;
          best = pk < best ? pk : best;
        }
#pragma unroll
        for (int off = 1; off < 16; off <<= 1) {
          unsigned lo32 = (unsigned)best, hi32 = (unsigned)(best >> 32);
          lo32 = __shfl_xor(lo32, off);
          hi32 = __shfl_xor(hi32, off);
          const u64 o2 = (((u64)hi32) << 32) | lo32;
          best = o2 < best ? o2 : best;
        }
        if (lm == 0) atomicMin(pmin + nloc, best);
      }
    }
  }
}

// ---------- row sumsq (tn) from bf16 hi/lo E rows ----------
__global__ __launch_bounds__(256) void k_rownorm(const u16* __restrict__ Eh,
                                                 const u16* __restrict__ El,
                                                 float* __restrict__ tn) {
  const int t = threadIdx.x;
  const int r = t >> 2, p = t & 3;
  const int n = blockIdx.x * 64 + r;
  const u16* ph = Eh + (size_t)n * 256 + p * 64;
  const u16* pl = El + (size_t)n * 256 + p * 64;
  float s = 0.f;
#pragma unroll
  for (int j = 0; j < 8; ++j) {
    const uint4 hv = *(const uint4*)(ph + j * 8);
    const uint4 lv = *(const uint4*)(pl + j * 8);
    const unsigned hu[4] = {hv.x, hv.y, hv.z, hv.w};
    const unsigned lu[4] = {lv.x, lv.y, lv.z, lv.w};
#pragma unroll
    for (int q = 0; q < 4; ++q) {
      const float v0 = b2f((u16)(hu[q] & 0xffff)) + b2f((u16)(lu[q] & 0xffff));
      const float v1 = b2f((u16)(hu[q] >> 16)) + b2f((u16)(lu[q] >> 16));
      s = fmaf(v0, v0, s);
      s = fmaf(v1, v1, s);
    }
  }
  s += __shfl_xor(s, 1);
  s += __shfl_xor(s, 2);
  if (p == 0) tn[n] = s;
}

// ---------- GRN scale s = 1 + gg*nx from sumsq ----------
__global__ __launch_bounds__(256) void k_grn_scale(const float* __restrict__ GX2,
                                                   const float* __restrict__ gg,
                                                   float* __restrict__ S, int b0) {
  const int b = b0 + blockIdx.x, t = threadIdx.x;
  const float* gxb = GX2 + (size_t)b * 1024;
  float gx[4];
  float s = 0.f;
#pragma unroll
  for (int i = 0; i < 4; ++i) {
    gx[i] = sqrtf(gxb[t + i * 256]);
    s += gx[i];
  }
  const int w = t >> 6, l = t & 63;
#pragma unroll
  for (int o = 32; o > 0; o >>= 1) s += __shfl_down(s, o);
  __shared__ float red[4];
  __shared__ float bc;
  if (l == 0) red[w] = s;
  __syncthreads();
  if (t == 0) bc = 1.0f / ((red[0] + red[1] + red[2] + red[3]) * (1.0f / 1024.0f) + 1e-6f);
  __syncthreads();
  const float inv = bc;
#pragma unroll
  for (int i = 0; i < 4; ++i)
    S[(size_t)b * 1024 + t + i * 256] = fmaf(gg[t + i * 256], gx[i] * inv, 1.0f);
}

// ---------- per-batch scaled+split+transposed W2 ----------
__global__ __launch_bounds__(256) void k_w2prep(const float* __restrict__ W2,
                                                const float* __restrict__ S, int b0,
                                                u16* __restrict__ Wh, u16* __restrict__ Wl) {
  const int bx = blockIdx.x;
  const int b = b0 + (bx >> 8), n = bx & 255;
  const int t = threadIdx.x;
#pragma unroll
  for (int j = 0; j < 4; ++j) {
    const int k = t + j * 256;
    const float v = W2[(size_t)k * 256 + n] * S[(size_t)b * 1024 + k];
    const size_t idx = ((size_t)(b * 256 + n)) * 1024 + k;
    const u16 h = bfhi(v);
    Wh[idx] = h;
    Wl[idx] = bfhi(v - b2f(h));
  }
}

// ---------- bias2v = b2 + gb @ W2 (one block per output channel) ----------
__global__ __launch_bounds__(256) void k_bias2(const float* __restrict__ W2,
                                               const float* __restrict__ gb,
                                               const float* __restrict__ b2,
                                               float* __restrict__ out) {
  const int c = blockIdx.x, t = threadIdx.x;
  float acc = 0.f;
#pragma unroll
  for (int j = 0; j < 4; ++j) {
    const int k = t + j * 256;
    acc = fmaf(gb[k], W2[(size_t)k * 256 + c], acc);
  }
  const int w = t >> 6, l = t & 63;
#pragma unroll
  for (int o = 32; o > 0; o >>= 1) acc += __shfl_down(acc, o);
  __shared__ float red[4];
  if (l == 0) red[w] = acc;
  __syncthreads();
  if (t == 0) out[c] = red[0] + red[1] + red[2] + red[3] + b2[c];
}

// ---------- W1^T split ----------
__global__ __launch_bounds__(256) void k_wt(const float* __restrict__ W1,
                                            u16* __restrict__ Wh, u16* __restrict__ Wl) {
  const int bx = blockIdx.x;  // d*1024 + n
  const int d = bx >> 10, n = bx & 1023;
  const int k = threadIdx.x;
  const float v = W1[(size_t)d * 262144 + (size_t)k * 1024 + n];
  const size_t idx = (size_t)bx * 256 + k;
  const u16 h = bfhi(v);
  Wh[idx] = h;
  Wl[idx] = bfhi(v - b2f(h));
}

// ---------- codebook split ----------
__global__ __launch_bounds__(256) void k_csplit(const float* __restrict__ C,
                                                u16* __restrict__ Ch, u16* __restrict__ Cl) {
  const size_t i = (size_t)blockIdx.x * 256 + threadIdx.x;
  const float v = C[i];
  const u16 h = bfhi(v);
  Ch[i] = h;
  Cl[i] = bfhi(v - b2f(h));
}

// ---------- numpy-pairwise |c|^2 per code ----------
__device__ __forceinline__ float np_pairwise_sq_256(const float* p) {
  float half[2];
#pragma unroll
  for (int hh = 0; hh < 2; ++hh) {
    float r[8];
#pragma unroll
    for (int j = 0; j < 8; ++j) {
      const float v = p[hh * 128 + j];
      r[j] = __fmul_rn(v, v);
    }
    for (int i = 8; i < 128; i += 8) {
#pragma unroll
      for (int j = 0; j < 8; ++j) {
        const float v = p[hh * 128 + i + j];
        r[j] = __fadd_rn(r[j], __fmul_rn(v, v));
      }
    }
    half[hh] = __fadd_rn(__fadd_rn(__fadd_rn(r[0], r[1]), __fadd_rn(r[2], r[3])),
                         __fadd_rn(__fadd_rn(r[4], r[5]), __fadd_rn(r[6], r[7])));
  }
  return __fadd_rn(half[0], half[1]);
}

__global__ __launch_bounds__(256) void k_c2(const float* __restrict__ cbk, float* __restrict__ c2) {
  const int k = blockIdx.x * 256 + threadIdx.x;
  c2[k] = np_pairwise_sq_256(cbk + (size_t)k * 256);
}

// ---------- index output + quantized gather ----------
__global__ __launch_bounds__(256) void k_idx(const u64* __restrict__ pk, float* __restrict__ outI) {
  const int n = blockIdx.x * 256 + threadIdx.x;
  outI[n] = (float)(unsigned)(pk[n] & 0xffffffffULL);
}

// 64 consecutive pixels per block; lanes = pixels so NCHW writes coalesce
__global__ __launch_bounds__(256) void k_gather(const u64* __restrict__ pk,
                                                const float* __restrict__ cbk,
                                                float* __restrict__ outq) {
  const int t = threadIdx.x;
  const int p0 = blockIdx.x * 64;
  const int b = p0 >> 12, pl = (p0 & 4095) + (t & 63);
  const int cg = t >> 6;  // 4 channel groups of 64
  const int n = p0 + (t & 63);
  const int k = (int)(unsigned)(pk[n] & 0xffffffffULL);
  const float* crow = cbk + (size_t)k * 256 + cg * 64;
  float* ob = outq + (((size_t)(b * 256 + cg * 64)) << 12) + pl;
#pragma unroll 1
  for (int j = 0; j < 16; ++j) {
    const float4 cv = *(const float4*)(crow + j * 4);
    ob[((size_t)(j * 4 + 0)) << 12] = cv.x;
    ob[((size_t)(j * 4 + 1)) << 12] = cv.y;
    ob[((size_t)(j * 4 + 2)) << 12] = cv.z;
    ob[((size_t)(j * 4 + 3)) << 12] = cv.w;
  }
}

extern "C" void kernel_launch(void* const* d_in, const int* in_sizes, int n_in,
                              void* d_out, int out_size, void* d_ws, size_t ws_size,
                              hipStream_t stream) {
  const float* x = (const float*)d_in[0];
  const float* cbk = (const float*)d_in[1];
  const float* Pe[10];
  const float* Pd[10];
  for (int i = 0; i < 10; ++i) Pe[i] = (const float*)d_in[2 + i];
  for (int i = 0; i < 10; ++i) Pd[i] = (const float*)d_in[12 + i];
  // order per dict: conv_w, conv_b, ln_g, ln_b, fc1_w, fc1_b, grn_g, grn_b, fc2_w, fc2_b

  float* ws = (float*)d_ws;
  size_t o = 0;
  auto alloc = [&](size_t nf) {
    float* p = ws + o;
    o += (nf + 63) & ~(size_t)63;
    return p;
  };
  float* P1 = alloc(8388608);      // NCHW ping
  u16* Rh = (u16*)alloc(4194304);  // rows hi (also E hi)
  u16* Rl = (u16*)alloc(4194304);  // rows lo (also E lo)
  u16* W1th_e = (u16*)alloc(262144);
  u16* W1tl_e = (u16*)alloc(262144);
  u16* W1th_d = (u16*)alloc(262144);
  u16* W1tl_d = (u16*)alloc(262144);
  u16* W2sh = (u16*)alloc(1048576);
  u16* W2sl = (u16*)alloc(1048576);
  u16* Ch = (u16*)alloc(131072);
  u16* Cl = (u16*)alloc(131072);
  float* C2v = alloc(1024);
  float* GX2 = alloc(8192);
  float* Sv = alloc(8192);
  float* bias2v = alloc(256);
  float* tn = alloc(32768);
  u64* pk = (u64*)alloc(65536);
  const size_t fixedf = o;
  const size_t availf = (ws_size / 4 > fixedf) ? ws_size / 4 - fixedf : 0;
  int chunkB = (int)(availf / 4194304);  // Mh+Ml per batch = 4M floats worth
  if (chunkB > 8) chunkB = 8;
  if (chunkB < 1) chunkB = 1;
  float* Cv = ws + o;  // conv NCHW fp32, aliases M arena (dead by fc1 time)
  u16* Mh = (u16*)(ws + o);
  u16* Ml = (u16*)(ws + o + (size_t)chunkB * 2097152);

  float* outQ = (float*)d_out;
  float* outD = outQ + 8388608;
  float* outI = outD + 8388608;

  auto run_enc = [&](const float* xin, float* xout, u16* Eh, u16* El,
                     const float* const* pp, int d) {
    k_conv<<<2048, 256, 0, stream>>>(xin, pp[0] + (size_t)d * 256 * 49, pp[1] + d * 256, Cv);
    k_lnT<<<1024, 256, 0, stream>>>(Cv, pp[2] + d * 256, pp[3] + d * 256, Rh, Rl, 1);
    k_bias2<<<256, 256, 0, stream>>>(pp[8] + (size_t)d * 262144, pp[7] + d * 1024,
                                     pp[9] + d * 256, bias2v);
    hipMemsetAsync(GX2, 0, 8192 * 4, stream);
    for (int b0 = 0; b0 < 8; b0 += chunkB) {
      const int nb = (8 - b0 < chunkB) ? 8 - b0 : chunkB;
      k_gemm<256, 1, 0><<<dim3(8, nb * 32), 256, 0, stream>>>(
          Rh + (size_t)b0 * 4096 * 256, Rl + (size_t)b0 * 4096 * 256,
          W1th_e + (size_t)d * 262144, W1tl_e + (size_t)d * 262144,
          b0 * 4096, 0, Pe[5] + d * 1024, Mh, Ml, nullptr, nullptr, GX2, nullptr);
      k_grn_scale<<<nb, 256, 0, stream>>>(GX2, pp[6] + d * 1024, Sv, b0);
      k_w2prep<<<nb * 256, 256, 0, stream>>>(pp[8] + (size_t)d * 262144, Sv, b0, W2sh, W2sl);
      k_gemm<1024, 1, 1><<<dim3(2, nb * 32), 256, 0, stream>>>(
          Mh, Ml, W2sh, W2sl, b0 * 4096, 262144LL, bias2v,
          Eh ? Eh + (size_t)b0 * 4096 * 256 : (u16*)nullptr,
          El ? El + (size_t)b0 * 4096 * 256 : (u16*)nullptr,
          xout, xin, nullptr, nullptr);
    }
  };

  auto run_dec = [&](const float* xin, float* xout, const float* const* pp, int d) {
    k_conv<<<2048, 256, 0, stream>>>(xin, pp[0] + (size_t)d * 256 * 49, pp[1] + d * 256, Cv);
    k_lnT<<<1024, 256, 0, stream>>>(Cv, pp[2] + d * 256, pp[3] + d * 256, Rh, Rl, 0);
    k_bias2<<<256, 256, 0, stream>>>(pp[8] + (size_t)d * 262144, pp[7] + d * 1024,
                                     pp[9] + d * 256, bias2v);
    hipMemsetAsync(GX2, 0, 8192 * 4, stream);
    for (int b0 = 0; b0 < 8; b0 += chunkB) {
      const int nb = (8 - b0 < chunkB) ? 8 - b0 : chunkB;
      k_gemm<256, 0, 0><<<dim3(8, nb * 32), 256, 0, stream>>>(
          Rh + (size_t)b0 * 4096 * 256, nullptr,
          W1th_d + (size_t)d * 262144, nullptr,
          b0 * 4096, 0, Pd[5] + d * 1024, Mh, nullptr, nullptr, nullptr, GX2, nullptr);
      k_grn_scale<<<nb, 256, 0, stream>>>(GX2, pp[6] + d * 1024, Sv, b0);
      k_w2prep<<<nb * 256, 256, 0, stream>>>(pp[8] + (size_t)d * 262144, Sv, b0, W2sh, W2sl);
      k_gemm<1024, 0, 1><<<dim3(2, nb * 32), 256, 0, stream>>>(
          Mh, nullptr, W2sh, nullptr, b0 * 4096, 262144LL, bias2v,
          nullptr, nullptr, xout, xin, nullptr, nullptr);
    }
  };

  // prep
  k_wt<<<2048, 256, 0, stream>>>(Pe[4], W1th_e, W1tl_e);
  k_wt<<<2048, 256, 0, stream>>>(Pd[4], W1th_d, W1tl_d);
  k_csplit<<<1024, 256, 0, stream>>>(cbk, Ch, Cl);
  k_c2<<<4, 256, 0, stream>>>(cbk, C2v);

  // encoder (split-bf16, fused 3-term)
  run_enc(x, P1, nullptr, nullptr, Pe, 0);
  run_enc(P1, nullptr, Rh, Rl, Pe, 1);  // E -> Rh/Rl, no NCHW out

  // VQ
  k_rownorm<<<512, 256, 0, stream>>>(Rh, Rl, tn);
  hipMemsetAsync(pk, 0xFF, 32768 * 8, stream);
  k_gemm<256, 1, 2><<<dim3(8, 256), 256, 0, stream>>>(Rh, Rl, Ch, Cl, 0, 0,
                                                      C2v, nullptr, nullptr, nullptr,
                                                      tn, nullptr, pk);
  k_idx<<<128, 256, 0, stream>>>(pk, outI);
  k_gather<<<512, 256, 0, stream>>>(pk, cbk, outQ);

  // decoder (plain bf16)
  run_dec(outQ, P1, Pd, 0);
  run_dec(P1, outD, Pd, 1);
}